// Round 1
// baseline (7288.506 us; speedup 1.0000x reference)
//
#include <hip/hip_runtime.h>
#include <math.h>

// Problem constants (fixed by the reference)
#define B_SZ   4
#define T_SEQ  1536
#define C_DIM  768
#define NH     12
#define HD     64          // C / NH
#define TBLK   512         // T / 3
#define M_ROWS (B_SZ * T_SEQ)   // 6144

#define ACT_NONE 0
#define ACT_SILU 1
#define ACT_GELU 2

// ---------------------------------------------------------------------------
// RMSNorm: out[row] = x[row] * rsqrt(mean(x^2) + eps) * g
// One 256-thread block per row of 768 floats (3 elems/thread).
// ---------------------------------------------------------------------------
__global__ __launch_bounds__(256) void rmsnorm_kernel(const float* __restrict__ x,
                                                      const float* __restrict__ g,
                                                      float* __restrict__ out) {
    const int row = blockIdx.x;
    const int tid = threadIdx.x;
    const float* xr = x + (size_t)row * C_DIM;

    const float v0 = xr[tid];
    const float v1 = xr[tid + 256];
    const float v2 = xr[tid + 512];
    float ss = v0 * v0 + v1 * v1 + v2 * v2;

    // wave(64) shuffle reduce, then cross-wave via LDS
    #pragma unroll
    for (int off = 32; off > 0; off >>= 1) ss += __shfl_xor(ss, off, 64);
    __shared__ float s_red[4];
    if ((tid & 63) == 0) s_red[tid >> 6] = ss;
    __syncthreads();
    ss = s_red[0] + s_red[1] + s_red[2] + s_red[3];

    const float r = rsqrtf(ss * (1.0f / C_DIM) + 1e-6f);
    float* orow = out + (size_t)row * C_DIM;
    orow[tid]       = v0 * r * g[tid];
    orow[tid + 256] = v1 * r * g[tid + 256];
    orow[tid + 512] = v2 * r * g[tid + 512];
}

// ---------------------------------------------------------------------------
// Fused GEMM: out = [resid +] act(A[*gate] @ W + bias)
//   A: [M,K] row-major, W: [K,N] row-major, bias: [N]
//   gate (optional): [M,K], multiplied into A on load
//   resid (optional): [M,N], added after activation
// Tiling: BM=64, BN=64, BK=16; 256 threads, 4x4 microtile per thread.
// M%64==0, N%64==0, K%16==0 hold for all call sites (6144, 768/3072, 768/3072).
// ---------------------------------------------------------------------------
#define BM 64
#define BN 64
#define BK 16

__global__ __launch_bounds__(256) void gemm_kernel(const float* __restrict__ A,
                                                   const float* __restrict__ W,
                                                   const float* __restrict__ bias,
                                                   const float* __restrict__ gate,
                                                   const float* __restrict__ resid,
                                                   float* __restrict__ out,
                                                   int M, int N, int K, int act) {
    __shared__ float As[BM][BK + 1];   // +1 pad: conflict-free column reads
    __shared__ float Bs[BK][BN];

    const int tid = threadIdx.x;
    const int tx = tid & 15;           // output col group (0..15)
    const int ty = tid >> 4;           // output row group (0..15)
    const int m0 = blockIdx.x * BM;
    const int n0 = blockIdx.y * BN;

    // A-tile load mapping: 64 rows x 16 cols, float4 per thread
    const int ar = tid >> 2;           // 0..63
    const int ac = (tid & 3) * 4;      // 0,4,8,12
    // B-tile load mapping: 16 rows x 64 cols, float4 per thread
    const int br = tid >> 4;           // 0..15
    const int bc = (tid & 15) * 4;     // 0..60

    float acc[4][4] = {};

    for (int k0 = 0; k0 < K; k0 += BK) {
        // global -> regs
        float4 a4 = *reinterpret_cast<const float4*>(&A[(size_t)(m0 + ar) * K + k0 + ac]);
        if (gate) {
            const float4 g4 = *reinterpret_cast<const float4*>(&gate[(size_t)(m0 + ar) * K + k0 + ac]);
            a4.x *= g4.x; a4.y *= g4.y; a4.z *= g4.z; a4.w *= g4.w;
        }
        const float4 b4 = *reinterpret_cast<const float4*>(&W[(size_t)(k0 + br) * N + n0 + bc]);

        __syncthreads();   // previous iteration's LDS reads done
        As[ar][ac + 0] = a4.x;
        As[ar][ac + 1] = a4.y;
        As[ar][ac + 2] = a4.z;
        As[ar][ac + 3] = a4.w;
        *reinterpret_cast<float4*>(&Bs[br][bc]) = b4;
        __syncthreads();

        #pragma unroll
        for (int kk = 0; kk < BK; ++kk) {
            float a[4];
            #pragma unroll
            for (int i = 0; i < 4; ++i) a[i] = As[ty * 4 + i][kk];
            const float4 bb = *reinterpret_cast<const float4*>(&Bs[kk][tx * 4]);
            const float b[4] = {bb.x, bb.y, bb.z, bb.w};
            #pragma unroll
            for (int i = 0; i < 4; ++i)
                #pragma unroll
                for (int j = 0; j < 4; ++j)
                    acc[i][j] += a[i] * b[j];
        }
    }

    // epilogue: bias -> activation -> residual -> float4 store
    const int colb = n0 + tx * 4;
    float bvals[4] = {0.f, 0.f, 0.f, 0.f};
    if (bias) {
        const float4 bb = *reinterpret_cast<const float4*>(&bias[colb]);
        bvals[0] = bb.x; bvals[1] = bb.y; bvals[2] = bb.z; bvals[3] = bb.w;
    }
    #pragma unroll
    for (int i = 0; i < 4; ++i) {
        const int r = m0 + ty * 4 + i;
        float vj[4];
        #pragma unroll
        for (int j = 0; j < 4; ++j) {
            float v = acc[i][j] + bvals[j];
            if (act == ACT_SILU) {
                v = v / (1.0f + expf(-v));
            } else if (act == ACT_GELU) {
                v = 0.5f * v * (1.0f + erff(v * 0.70710678118654752f));
            }
            vj[j] = v;
        }
        if (resid) {
            const float4 rr = *reinterpret_cast<const float4*>(&resid[(size_t)r * N + colb]);
            vj[0] += rr.x; vj[1] += rr.y; vj[2] += rr.z; vj[3] += rr.w;
        }
        float4 o; o.x = vj[0]; o.y = vj[1]; o.z = vj[2]; o.w = vj[3];
        *reinterpret_cast<float4*>(&out[(size_t)r * N + colb]) = o;
    }
}

// ---------------------------------------------------------------------------
// Block-causal attention.
// q,k,v,y: [B, T, C] with head h at columns h*64..h*64+63.
// Mask: query i attends key j iff (j % 512) <= (i % 512)  (tiled 3x3 tril).
// One 256-thread block (4 waves) per (b, h, i):
//   phase 1: wave w computes scores for keys j = w, w+4, ... (64-lane dot).
//   phase 2/3: block softmax over scores in LDS.
//   phase 4: PV; lane d accumulates y[d] over its wave's keys, reduce 4 waves.
// ---------------------------------------------------------------------------
__global__ __launch_bounds__(256) void attn_kernel(const float* __restrict__ q,
                                                   const float* __restrict__ k,
                                                   const float* __restrict__ v,
                                                   float* __restrict__ y) {
    const int i = blockIdx.x;
    const int h = blockIdx.y;
    const int b = blockIdx.z;
    const int lane = threadIdx.x & 63;
    const int wave = threadIdx.x >> 6;
    const int imod = i & (TBLK - 1);

    __shared__ float s_p[T_SEQ];
    __shared__ float s_red[8];
    __shared__ float s_y[4][HD];

    const float qv = q[((size_t)(b * T_SEQ + i)) * C_DIM + h * HD + lane];
    const float scale = 0.125f;   // 1/sqrt(64)

    // phase 1: masked scores
    const float* kbase = k + (size_t)b * T_SEQ * C_DIM + h * HD;
    for (int j = wave; j < T_SEQ; j += 4) {
        if ((j & (TBLK - 1)) <= imod) {          // wave-uniform branch
            float prod = qv * kbase[(size_t)j * C_DIM + lane];
            #pragma unroll
            for (int off = 32; off > 0; off >>= 1) prod += __shfl_xor(prod, off, 64);
            if (lane == 0) s_p[j] = prod * scale;
        } else {
            if (lane == 0) s_p[j] = -INFINITY;
        }
    }
    __syncthreads();

    // phase 2: row max
    float m = -INFINITY;
    for (int j = threadIdx.x; j < T_SEQ; j += 256) m = fmaxf(m, s_p[j]);
    #pragma unroll
    for (int off = 32; off > 0; off >>= 1) m = fmaxf(m, __shfl_xor(m, off, 64));
    if (lane == 0) s_red[wave] = m;
    __syncthreads();
    m = fmaxf(fmaxf(s_red[0], s_red[1]), fmaxf(s_red[2], s_red[3]));

    // phase 3: exp + sum  (exp(-inf - m) = 0 handles masked entries)
    float sum = 0.f;
    for (int j = threadIdx.x; j < T_SEQ; j += 256) {
        const float p = expf(s_p[j] - m);
        s_p[j] = p;
        sum += p;
    }
    #pragma unroll
    for (int off = 32; off > 0; off >>= 1) sum += __shfl_xor(sum, off, 64);
    if (lane == 0) s_red[4 + wave] = sum;
    __syncthreads();
    const float inv = 1.0f / (s_red[4] + s_red[5] + s_red[6] + s_red[7]);

    // phase 4: PV
    const float* vbase = v + (size_t)b * T_SEQ * C_DIM + h * HD;
    float acc = 0.f;
    for (int j = wave; j < T_SEQ; j += 4) {
        if ((j & (TBLK - 1)) <= imod) {
            acc += s_p[j] * vbase[(size_t)j * C_DIM + lane];
        }
    }
    s_y[wave][lane] = acc;
    __syncthreads();
    if (wave == 0) {
        const float r = (s_y[0][lane] + s_y[1][lane] + s_y[2][lane] + s_y[3][lane]) * inv;
        y[((size_t)(b * T_SEQ + i)) * C_DIM + h * HD + lane] = r;
    }
}

// ---------------------------------------------------------------------------
// Launcher.
// Workspace layout (unit U = 6144*768 floats = 18,874,368 B; 9 units = 170 MB):
//   unit 0: h                     (later free)
//   unit 1: act_res               (needed until gated out-proj)
//   unit 2: u        -> later yp
//   unit 3: q        -> later x1
//   unit 4: k        -> later m
//   unit 5: v        -+
//   unit 6: y         +-> later a1 (units 5..8, 6144x3072)
//   units 7,8:       -+
// ---------------------------------------------------------------------------
extern "C" void kernel_launch(void* const* d_in, const int* in_sizes, int n_in,
                              void* d_out, int out_size, void* d_ws, size_t ws_size,
                              hipStream_t stream) {
    const float* x     = (const float*)d_in[0];
    const float* g1    = (const float*)d_in[1];
    const float* g2    = (const float*)d_in[2];
    const float* W_in  = (const float*)d_in[3];
    const float* b_in  = (const float*)d_in[4];
    const float* W_act = (const float*)d_in[5];
    const float* b_act = (const float*)d_in[6];
    const float* W_out = (const float*)d_in[7];
    const float* b_out = (const float*)d_in[8];
    const float* Wq    = (const float*)d_in[9];
    const float* bq    = (const float*)d_in[10];
    const float* Wk    = (const float*)d_in[11];
    const float* bk    = (const float*)d_in[12];
    const float* Wv    = (const float*)d_in[13];
    const float* bv    = (const float*)d_in[14];
    const float* Wp    = (const float*)d_in[15];
    const float* bp    = (const float*)d_in[16];
    const float* W1    = (const float*)d_in[17];
    const float* b1    = (const float*)d_in[18];
    const float* W2    = (const float*)d_in[19];
    const float* b2    = (const float*)d_in[20];
    float* out = (float*)d_out;

    float* ws = (float*)d_ws;
    const size_t U = (size_t)M_ROWS * C_DIM;
    float* h_buf   = ws + 0 * U;
    float* act_buf = ws + 1 * U;
    float* u_buf   = ws + 2 * U;
    float* q_buf   = ws + 3 * U;
    float* k_buf   = ws + 4 * U;
    float* v_buf   = ws + 5 * U;
    float* y_buf   = ws + 6 * U;
    float* yp_buf  = ws + 2 * U;   // reuse u
    float* x1_buf  = ws + 3 * U;   // reuse q
    float* m_buf   = ws + 4 * U;   // reuse k
    float* a1_buf  = ws + 5 * U;   // reuse v,y + 2 more units (6144 x 3072)

    const dim3 blk(256);
    const dim3 grid_cc(M_ROWS / BM, C_DIM / BN);        // 96 x 12
    const dim3 grid_c4(M_ROWS / BM, (4 * C_DIM) / BN);  // 96 x 48
    const dim3 grid_attn(T_SEQ, NH, B_SZ);

    // h = rmsnorm(x, g1)
    rmsnorm_kernel<<<M_ROWS, blk, 0, stream>>>(x, g1, h_buf);
    // act_res = silu(h @ W_act + b_act); u = silu(h @ W_in + b_in)
    gemm_kernel<<<grid_cc, blk, 0, stream>>>(h_buf, W_act, b_act, nullptr, nullptr,
                                             act_buf, M_ROWS, C_DIM, C_DIM, ACT_SILU);
    gemm_kernel<<<grid_cc, blk, 0, stream>>>(h_buf, W_in, b_in, nullptr, nullptr,
                                             u_buf, M_ROWS, C_DIM, C_DIM, ACT_SILU);
    // q, k, v projections
    gemm_kernel<<<grid_cc, blk, 0, stream>>>(u_buf, Wq, bq, nullptr, nullptr,
                                             q_buf, M_ROWS, C_DIM, C_DIM, ACT_NONE);
    gemm_kernel<<<grid_cc, blk, 0, stream>>>(u_buf, Wk, bk, nullptr, nullptr,
                                             k_buf, M_ROWS, C_DIM, C_DIM, ACT_NONE);
    gemm_kernel<<<grid_cc, blk, 0, stream>>>(u_buf, Wv, bv, nullptr, nullptr,
                                             v_buf, M_ROWS, C_DIM, C_DIM, ACT_NONE);
    // y = blockcausal_attention(q, k, v)
    attn_kernel<<<grid_attn, blk, 0, stream>>>(q_buf, k_buf, v_buf, y_buf);
    // yp = y @ Wp + bp
    gemm_kernel<<<grid_cc, blk, 0, stream>>>(y_buf, Wp, bp, nullptr, nullptr,
                                             yp_buf, M_ROWS, C_DIM, C_DIM, ACT_NONE);
    // x1 = x + (yp * act_res) @ W_out + b_out   (gate fused into A-load)
    gemm_kernel<<<grid_cc, blk, 0, stream>>>(yp_buf, W_out, b_out, act_buf, x,
                                             x1_buf, M_ROWS, C_DIM, C_DIM, ACT_NONE);
    // m = rmsnorm(x1, g2)
    rmsnorm_kernel<<<M_ROWS, blk, 0, stream>>>(x1_buf, g2, m_buf);
    // a1 = gelu(m @ W1 + b1)
    gemm_kernel<<<grid_c4, blk, 0, stream>>>(m_buf, W1, b1, nullptr, nullptr,
                                             a1_buf, M_ROWS, 4 * C_DIM, C_DIM, ACT_GELU);
    // out = x1 + a1 @ W2 + b2
    gemm_kernel<<<grid_cc, blk, 0, stream>>>(a1_buf, W2, b2, nullptr, x1_buf,
                                             out, M_ROWS, C_DIM, 4 * C_DIM, ACT_NONE);
}

// Round 2
// 2423.459 us; speedup vs baseline: 3.0075x; 3.0075x over previous
//
#include <hip/hip_runtime.h>
#include <math.h>

// Problem constants (fixed by the reference)
#define B_SZ   4
#define T_SEQ  1536
#define C_DIM  768
#define NH     12
#define HD     64          // C / NH
#define TBLK   512         // T / 3
#define M_ROWS (B_SZ * T_SEQ)   // 6144

#define ACT_NONE 0
#define ACT_SILU 1
#define ACT_GELU 2

// ---------------------------------------------------------------------------
// RMSNorm: out[row] = x[row] * rsqrt(mean(x^2) + eps) * g
// ---------------------------------------------------------------------------
__global__ __launch_bounds__(256) void rmsnorm_kernel(const float* __restrict__ x,
                                                      const float* __restrict__ g,
                                                      float* __restrict__ out) {
    const int row = blockIdx.x;
    const int tid = threadIdx.x;
    const float* xr = x + (size_t)row * C_DIM;

    const float v0 = xr[tid];
    const float v1 = xr[tid + 256];
    const float v2 = xr[tid + 512];
    float ss = v0 * v0 + v1 * v1 + v2 * v2;

    #pragma unroll
    for (int off = 32; off > 0; off >>= 1) ss += __shfl_xor(ss, off, 64);
    __shared__ float s_red[4];
    if ((tid & 63) == 0) s_red[tid >> 6] = ss;
    __syncthreads();
    ss = s_red[0] + s_red[1] + s_red[2] + s_red[3];

    const float r = rsqrtf(ss * (1.0f / C_DIM) + 1e-6f);
    float* orow = out + (size_t)row * C_DIM;
    orow[tid]       = v0 * r * g[tid];
    orow[tid + 256] = v1 * r * g[tid + 256];
    orow[tid + 512] = v2 * r * g[tid + 512];
}

// ---------------------------------------------------------------------------
// Fused GEMM: out = [resid +] act(A[*gate] @ W + bias)  (unchanged from R0)
// ---------------------------------------------------------------------------
#define BM 64
#define BN 64
#define BK 16

__global__ __launch_bounds__(256) void gemm_kernel(const float* __restrict__ A,
                                                   const float* __restrict__ W,
                                                   const float* __restrict__ bias,
                                                   const float* __restrict__ gate,
                                                   const float* __restrict__ resid,
                                                   float* __restrict__ out,
                                                   int M, int N, int K, int act) {
    __shared__ float As[BM][BK + 1];
    __shared__ float Bs[BK][BN];

    const int tid = threadIdx.x;
    const int tx = tid & 15;
    const int ty = tid >> 4;
    const int m0 = blockIdx.x * BM;
    const int n0 = blockIdx.y * BN;

    const int ar = tid >> 2;
    const int ac = (tid & 3) * 4;
    const int br = tid >> 4;
    const int bc = (tid & 15) * 4;

    float acc[4][4] = {};

    for (int k0 = 0; k0 < K; k0 += BK) {
        float4 a4 = *reinterpret_cast<const float4*>(&A[(size_t)(m0 + ar) * K + k0 + ac]);
        if (gate) {
            const float4 g4 = *reinterpret_cast<const float4*>(&gate[(size_t)(m0 + ar) * K + k0 + ac]);
            a4.x *= g4.x; a4.y *= g4.y; a4.z *= g4.z; a4.w *= g4.w;
        }
        const float4 b4 = *reinterpret_cast<const float4*>(&W[(size_t)(k0 + br) * N + n0 + bc]);

        __syncthreads();
        As[ar][ac + 0] = a4.x;
        As[ar][ac + 1] = a4.y;
        As[ar][ac + 2] = a4.z;
        As[ar][ac + 3] = a4.w;
        *reinterpret_cast<float4*>(&Bs[br][bc]) = b4;
        __syncthreads();

        #pragma unroll
        for (int kk = 0; kk < BK; ++kk) {
            float a[4];
            #pragma unroll
            for (int i = 0; i < 4; ++i) a[i] = As[ty * 4 + i][kk];
            const float4 bb = *reinterpret_cast<const float4*>(&Bs[kk][tx * 4]);
            const float b[4] = {bb.x, bb.y, bb.z, bb.w};
            #pragma unroll
            for (int i = 0; i < 4; ++i)
                #pragma unroll
                for (int j = 0; j < 4; ++j)
                    acc[i][j] += a[i] * b[j];
        }
    }

    const int colb = n0 + tx * 4;
    float bvals[4] = {0.f, 0.f, 0.f, 0.f};
    if (bias) {
        const float4 bb = *reinterpret_cast<const float4*>(&bias[colb]);
        bvals[0] = bb.x; bvals[1] = bb.y; bvals[2] = bb.z; bvals[3] = bb.w;
    }
    #pragma unroll
    for (int i = 0; i < 4; ++i) {
        const int r = m0 + ty * 4 + i;
        float vj[4];
        #pragma unroll
        for (int j = 0; j < 4; ++j) {
            float v = acc[i][j] + bvals[j];
            if (act == ACT_SILU) {
                v = v / (1.0f + expf(-v));
            } else if (act == ACT_GELU) {
                v = 0.5f * v * (1.0f + erff(v * 0.70710678118654752f));
            }
            vj[j] = v;
        }
        if (resid) {
            const float4 rr = *reinterpret_cast<const float4*>(&resid[(size_t)r * N + colb]);
            vj[0] += rr.x; vj[1] += rr.y; vj[2] += rr.z; vj[3] += rr.w;
        }
        float4 o; o.x = vj[0]; o.y = vj[1]; o.z = vj[2]; o.w = vj[3];
        *reinterpret_cast<float4*>(&out[(size_t)r * N + colb]) = o;
    }
}

// ---------------------------------------------------------------------------
// Tiled block-causal flash attention (fp32, VALU).
// One block = one (b, h, 64-query tile). 256 threads, 4x4 microtile.
// S-tile = Qt^T-style GEMM from LDS (all b128 reads); online softmax in regs
// (row stats shared across the 16-lane tx-group via shfl_xor width=16);
// P written transposed into the K buffer; PV GEMM from LDS.
// Mask structure: q-tile at position qb (mod 512-block) needs key tiles
// jt=0..qb in each of the 3 key blocks; only jt==qb applies the tril mask.
// LDS = 3 * 64*68*4 = 52 KB -> 3 blocks/CU.
// ---------------------------------------------------------------------------
#define ATT_PAD 4
__global__ __launch_bounds__(256) void attn_kernel(const float* __restrict__ q,
                                                   const float* __restrict__ k,
                                                   const float* __restrict__ v,
                                                   float* __restrict__ y) {
    __shared__ float Qt[HD][64 + ATT_PAD];   // Qt[d][query]  (scaled)
    __shared__ float Kt[HD][64 + ATT_PAD];   // Kt[d][key], reused as Pt[key][query]
    __shared__ float Vs[64][HD + ATT_PAD];   // Vs[key][d]

    const int tid = threadIdx.x;
    const int tx = tid & 15;          // 0..15
    const int ty = tid >> 4;          // 0..15
    const int qt = blockIdx.x;        // 0..23
    const int h  = blockIdx.y;
    const int b  = blockIdx.z;
    const int i0 = qt * 64;
    const int qb = qt & 7;            // q-tile index within its 512 block

    const size_t headoff = (size_t)b * T_SEQ * C_DIM + (size_t)h * HD;
    const float* qp = q + headoff;
    const float* kp = k + headoff;
    const float* vp = v + headoff;

    // ---- load Q tile transposed & scaled: thread owns 4 dims x 4 queries ----
    {
        const int jb4 = tx * 4;       // query group
        const int db4 = ty * 4;       // dim group
        const float sc = 0.125f;      // 1/sqrt(64)
        float4 r0 = *reinterpret_cast<const float4*>(&qp[(size_t)(i0 + jb4 + 0) * C_DIM + db4]);
        float4 r1 = *reinterpret_cast<const float4*>(&qp[(size_t)(i0 + jb4 + 1) * C_DIM + db4]);
        float4 r2 = *reinterpret_cast<const float4*>(&qp[(size_t)(i0 + jb4 + 2) * C_DIM + db4]);
        float4 r3 = *reinterpret_cast<const float4*>(&qp[(size_t)(i0 + jb4 + 3) * C_DIM + db4]);
        *reinterpret_cast<float4*>(&Qt[db4 + 0][jb4]) = make_float4(r0.x*sc, r1.x*sc, r2.x*sc, r3.x*sc);
        *reinterpret_cast<float4*>(&Qt[db4 + 1][jb4]) = make_float4(r0.y*sc, r1.y*sc, r2.y*sc, r3.y*sc);
        *reinterpret_cast<float4*>(&Qt[db4 + 2][jb4]) = make_float4(r0.z*sc, r1.z*sc, r2.z*sc, r3.z*sc);
        *reinterpret_cast<float4*>(&Qt[db4 + 3][jb4]) = make_float4(r0.w*sc, r1.w*sc, r2.w*sc, r3.w*sc);
    }

    float o[4][4] = {};
    float m_run[4] = {-INFINITY, -INFINITY, -INFINITY, -INFINITY};
    float l_run[4] = {0.f, 0.f, 0.f, 0.f};

    for (int kb = 0; kb < 3; ++kb) {
        for (int jt = 0; jt <= qb; ++jt) {
            const int j0 = kb * TBLK + jt * 64;
            const bool masked = (jt == qb);

            __syncthreads();   // (A) previous PV done with Kt(=Pt)/Vs

            // ---- load K transposed (4 dims x 4 keys per thread) ----
            {
                const int jb4 = tx * 4;
                const int db4 = ty * 4;
                float4 r0 = *reinterpret_cast<const float4*>(&kp[(size_t)(j0 + jb4 + 0) * C_DIM + db4]);
                float4 r1 = *reinterpret_cast<const float4*>(&kp[(size_t)(j0 + jb4 + 1) * C_DIM + db4]);
                float4 r2 = *reinterpret_cast<const float4*>(&kp[(size_t)(j0 + jb4 + 2) * C_DIM + db4]);
                float4 r3 = *reinterpret_cast<const float4*>(&kp[(size_t)(j0 + jb4 + 3) * C_DIM + db4]);
                *reinterpret_cast<float4*>(&Kt[db4 + 0][jb4]) = make_float4(r0.x, r1.x, r2.x, r3.x);
                *reinterpret_cast<float4*>(&Kt[db4 + 1][jb4]) = make_float4(r0.y, r1.y, r2.y, r3.y);
                *reinterpret_cast<float4*>(&Kt[db4 + 2][jb4]) = make_float4(r0.z, r1.z, r2.z, r3.z);
                *reinterpret_cast<float4*>(&Kt[db4 + 3][jb4]) = make_float4(r0.w, r1.w, r2.w, r3.w);
                // V rows (row-major)
                const int vc = tx * 4;
                #pragma unroll
                for (int l = 0; l < 4; ++l) {
                    const int r = ty + 16 * l;
                    *reinterpret_cast<float4*>(&Vs[r][vc]) =
                        *reinterpret_cast<const float4*>(&vp[(size_t)(j0 + r) * C_DIM + vc]);
                }
            }
            __syncthreads();   // (B) tiles ready

            // ---- S = Q K^T (rows=queries via ty, cols=keys via tx) ----
            float s[4][4] = {};
            #pragma unroll
            for (int d = 0; d < HD; ++d) {
                const float4 a  = *reinterpret_cast<const float4*>(&Qt[d][ty * 4]);
                const float4 bb = *reinterpret_cast<const float4*>(&Kt[d][tx * 4]);
                const float av[4] = {a.x, a.y, a.z, a.w};
                const float bv[4] = {bb.x, bb.y, bb.z, bb.w};
                #pragma unroll
                for (int i = 0; i < 4; ++i)
                    #pragma unroll
                    for (int j = 0; j < 4; ++j)
                        s[i][j] += av[i] * bv[j];
            }

            if (masked) {
                #pragma unroll
                for (int i = 0; i < 4; ++i)
                    #pragma unroll
                    for (int j = 0; j < 4; ++j)
                        if (tx * 4 + j > ty * 4 + i) s[i][j] = -INFINITY;
            }

            // ---- online softmax (row group = 16 lanes sharing ty) ----
            #pragma unroll
            for (int i = 0; i < 4; ++i) {
                float rm = fmaxf(fmaxf(s[i][0], s[i][1]), fmaxf(s[i][2], s[i][3]));
                #pragma unroll
                for (int off = 1; off < 16; off <<= 1) rm = fmaxf(rm, __shfl_xor(rm, off, 16));
                const float mn = fmaxf(m_run[i], rm);
                const float sc = expf(m_run[i] - mn);   // 0 when m_run = -inf
                float rs = 0.f;
                #pragma unroll
                for (int j = 0; j < 4; ++j) {
                    const float pv = expf(s[i][j] - mn);  // masked -> exp(-inf)=0
                    s[i][j] = pv;
                    rs += pv;
                }
                #pragma unroll
                for (int off = 1; off < 16; off <<= 1) rs += __shfl_xor(rs, off, 16);
                l_run[i] = l_run[i] * sc + rs;
                m_run[i] = mn;
                #pragma unroll
                for (int j = 0; j < 4; ++j) o[i][j] *= sc;
            }

            __syncthreads();   // (C) all threads done reading Kt

            // ---- write P transposed into Kt: Pt[key][query] ----
            *reinterpret_cast<float4*>(&Kt[tx * 4 + 0][ty * 4]) = make_float4(s[0][0], s[1][0], s[2][0], s[3][0]);
            *reinterpret_cast<float4*>(&Kt[tx * 4 + 1][ty * 4]) = make_float4(s[0][1], s[1][1], s[2][1], s[3][1]);
            *reinterpret_cast<float4*>(&Kt[tx * 4 + 2][ty * 4]) = make_float4(s[0][2], s[1][2], s[2][2], s[3][2]);
            *reinterpret_cast<float4*>(&Kt[tx * 4 + 3][ty * 4]) = make_float4(s[0][3], s[1][3], s[2][3], s[3][3]);

            __syncthreads();   // (D) Pt ready

            // ---- O += P V (rows=queries via ty, cols=dims via tx) ----
            #pragma unroll
            for (int jj = 0; jj < 64; ++jj) {
                const float4 a  = *reinterpret_cast<const float4*>(&Kt[jj][ty * 4]);
                const float4 bb = *reinterpret_cast<const float4*>(&Vs[jj][tx * 4]);
                const float av[4] = {a.x, a.y, a.z, a.w};
                const float bv[4] = {bb.x, bb.y, bb.z, bb.w};
                #pragma unroll
                for (int i = 0; i < 4; ++i)
                    #pragma unroll
                    for (int j = 0; j < 4; ++j)
                        o[i][j] += av[i] * bv[j];
            }
        }
    }

    // ---- normalize + store ----
    #pragma unroll
    for (int i = 0; i < 4; ++i) {
        const float inv = 1.0f / l_run[i];
        const int row = i0 + ty * 4 + i;
        float4 o4;
        o4.x = o[i][0] * inv; o4.y = o[i][1] * inv;
        o4.z = o[i][2] * inv; o4.w = o[i][3] * inv;
        *reinterpret_cast<float4*>(&y[headoff + (size_t)row * C_DIM + tx * 4]) = o4;
    }
}

// ---------------------------------------------------------------------------
// Launcher.
// ---------------------------------------------------------------------------
extern "C" void kernel_launch(void* const* d_in, const int* in_sizes, int n_in,
                              void* d_out, int out_size, void* d_ws, size_t ws_size,
                              hipStream_t stream) {
    const float* x     = (const float*)d_in[0];
    const float* g1    = (const float*)d_in[1];
    const float* g2    = (const float*)d_in[2];
    const float* W_in  = (const float*)d_in[3];
    const float* b_in  = (const float*)d_in[4];
    const float* W_act = (const float*)d_in[5];
    const float* b_act = (const float*)d_in[6];
    const float* W_out = (const float*)d_in[7];
    const float* b_out = (const float*)d_in[8];
    const float* Wq    = (const float*)d_in[9];
    const float* bq    = (const float*)d_in[10];
    const float* Wk    = (const float*)d_in[11];
    const float* bk    = (const float*)d_in[12];
    const float* Wv    = (const float*)d_in[13];
    const float* bv    = (const float*)d_in[14];
    const float* Wp    = (const float*)d_in[15];
    const float* bp    = (const float*)d_in[16];
    const float* W1    = (const float*)d_in[17];
    const float* b1    = (const float*)d_in[18];
    const float* W2    = (const float*)d_in[19];
    const float* b2    = (const float*)d_in[20];
    float* out = (float*)d_out;

    float* ws = (float*)d_ws;
    const size_t U = (size_t)M_ROWS * C_DIM;
    float* h_buf   = ws + 0 * U;
    float* act_buf = ws + 1 * U;
    float* u_buf   = ws + 2 * U;
    float* q_buf   = ws + 3 * U;
    float* k_buf   = ws + 4 * U;
    float* v_buf   = ws + 5 * U;
    float* y_buf   = ws + 6 * U;
    float* yp_buf  = ws + 2 * U;   // reuse u
    float* x1_buf  = ws + 3 * U;   // reuse q
    float* m_buf   = ws + 4 * U;   // reuse k
    float* a1_buf  = ws + 5 * U;   // reuse v,y + 2 more units (6144 x 3072)

    const dim3 blk(256);
    const dim3 grid_cc(M_ROWS / BM, C_DIM / BN);
    const dim3 grid_c4(M_ROWS / BM, (4 * C_DIM) / BN);
    const dim3 grid_attn(T_SEQ / 64, NH, B_SZ);

    rmsnorm_kernel<<<M_ROWS, blk, 0, stream>>>(x, g1, h_buf);
    gemm_kernel<<<grid_cc, blk, 0, stream>>>(h_buf, W_act, b_act, nullptr, nullptr,
                                             act_buf, M_ROWS, C_DIM, C_DIM, ACT_SILU);
    gemm_kernel<<<grid_cc, blk, 0, stream>>>(h_buf, W_in, b_in, nullptr, nullptr,
                                             u_buf, M_ROWS, C_DIM, C_DIM, ACT_SILU);
    gemm_kernel<<<grid_cc, blk, 0, stream>>>(u_buf, Wq, bq, nullptr, nullptr,
                                             q_buf, M_ROWS, C_DIM, C_DIM, ACT_NONE);
    gemm_kernel<<<grid_cc, blk, 0, stream>>>(u_buf, Wk, bk, nullptr, nullptr,
                                             k_buf, M_ROWS, C_DIM, C_DIM, ACT_NONE);
    gemm_kernel<<<grid_cc, blk, 0, stream>>>(u_buf, Wv, bv, nullptr, nullptr,
                                             v_buf, M_ROWS, C_DIM, C_DIM, ACT_NONE);
    attn_kernel<<<grid_attn, blk, 0, stream>>>(q_buf, k_buf, v_buf, y_buf);
    gemm_kernel<<<grid_cc, blk, 0, stream>>>(y_buf, Wp, bp, nullptr, nullptr,
                                             yp_buf, M_ROWS, C_DIM, C_DIM, ACT_NONE);
    gemm_kernel<<<grid_cc, blk, 0, stream>>>(yp_buf, W_out, b_out, act_buf, x,
                                             x1_buf, M_ROWS, C_DIM, C_DIM, ACT_NONE);
    rmsnorm_kernel<<<M_ROWS, blk, 0, stream>>>(x1_buf, g2, m_buf);
    gemm_kernel<<<grid_c4, blk, 0, stream>>>(m_buf, W1, b1, nullptr, nullptr,
                                             a1_buf, M_ROWS, 4 * C_DIM, C_DIM, ACT_GELU);
    gemm_kernel<<<grid_cc, blk, 0, stream>>>(a1_buf, W2, b2, nullptr, x1_buf,
                                             out, M_ROWS, C_DIM, 4 * C_DIM, ACT_NONE);
}

// Round 5
// 1173.989 us; speedup vs baseline: 6.2083x; 2.0643x over previous
//
#include <hip/hip_runtime.h>
#include <math.h>

// Problem constants (fixed by the reference)
#define B_SZ   4
#define T_SEQ  1536
#define C_DIM  768
#define NH     12
#define HD     64
#define TBLK   512
#define M_ROWS (B_SZ * T_SEQ)   // 6144

// epilogue mode: low 3 bits = activation, bit 3 = write bf16 (else f32)
#define ACT_NONE 0
#define ACT_SILU 1
#define ACT_GELU 2
#define OUT_BF16 8

typedef __attribute__((ext_vector_type(8))) short bf16x8;
typedef __attribute__((ext_vector_type(4))) float f32x4;

static __device__ __forceinline__ void gload_lds16(const void* g, void* l) {
    __builtin_amdgcn_global_load_lds(
        (const __attribute__((address_space(1))) void*)g,
        (__attribute__((address_space(3))) void*)l, 16, 0, 0);
}

// round-to-nearest-even f32 -> bf16 (bit pattern)
static __device__ __forceinline__ unsigned short f2bf(float f) {
    unsigned int u = __float_as_uint(f);
    u += 0x7fffu + ((u >> 16) & 1u);
    return (unsigned short)(u >> 16);
}

// ---------------------------------------------------------------------------
// Weight transpose + bf16 convert: W [K][N] f32 -> Wt [N][K] bf16
// block (32,8), grid (N/32, K/32)
// ---------------------------------------------------------------------------
__global__ __launch_bounds__(256) void wtrans_kernel(const float* in, unsigned short* out, int K, int N) {
    __shared__ float t[32][33];
    const int tx = threadIdx.x, ty = threadIdx.y;
    const int n0 = blockIdx.x * 32, k0 = blockIdx.y * 32;
    #pragma unroll
    for (int j = 0; j < 4; ++j)
        t[ty + 8 * j][tx] = in[(size_t)(k0 + ty + 8 * j) * N + n0 + tx];
    __syncthreads();
    #pragma unroll
    for (int j = 0; j < 4; ++j)
        out[(size_t)(n0 + ty + 8 * j) * K + k0 + tx] = f2bf(t[tx][ty + 8 * j]);
}

// ---------------------------------------------------------------------------
// RMSNorm -> bf16 output
// ---------------------------------------------------------------------------
__global__ __launch_bounds__(256) void rmsnorm_kernel(const float* x, const float* g, unsigned short* out) {
    const int row = blockIdx.x;
    const int tid = threadIdx.x;
    const float* xr = x + (size_t)row * C_DIM;

    const float v0 = xr[tid];
    const float v1 = xr[tid + 256];
    const float v2 = xr[tid + 512];
    float ss = v0 * v0 + v1 * v1 + v2 * v2;

    #pragma unroll
    for (int off = 32; off > 0; off >>= 1) ss += __shfl_xor(ss, off, 64);
    __shared__ float s_red[4];
    if ((tid & 63) == 0) s_red[tid >> 6] = ss;
    __syncthreads();
    ss = s_red[0] + s_red[1] + s_red[2] + s_red[3];

    const float r = rsqrtf(ss * (1.0f / C_DIM) + 1e-6f);
    unsigned short* orow = out + (size_t)row * C_DIM;
    orow[tid]       = f2bf(v0 * r * g[tid]);
    orow[tid + 256] = f2bf(v1 * r * g[tid + 256]);
    orow[tid + 512] = f2bf(v2 * r * g[tid + 512]);
}

// ---------------------------------------------------------------------------
// bf16 MFMA GEMM: out = [resid +] ( act(A @ Bt^T + bias) [* gmul] )
//   A  [M][K] bf16, Bt [N][K] bf16 (pre-transposed weight)
//   bias [N] f32; gmul [M][N] f32; resid [M][N] f32; outp -> f32 or bf16
// Tile 128x128, BK=64, 4 waves (2x2), 16x16x32 MFMA, 4x4 frags/wave.
// LDS 32 KB, staged via global_load_lds width 16 (linear layout).
// ---------------------------------------------------------------------------
#define GBM 128
#define GBN 128
#define GBK 64

__global__ __launch_bounds__(256) void gemm_bf16(const unsigned short* A, const unsigned short* Bt, const float* bias, const float* gmul, const float* resid, void* outp, int M, int N, int K, int mode) {
    __shared__ unsigned short As[GBM * GBK];
    __shared__ unsigned short Bs[GBN * GBK];

    const int tid  = threadIdx.x;
    const int lane = tid & 63;
    const int wid  = tid >> 6;
    const int wr   = wid >> 1;
    const int wc   = wid & 1;
    const int m0   = blockIdx.x * GBM;
    const int n0   = blockIdx.y * GBN;

    const int l15 = lane & 15;
    const int l4  = lane >> 4;

    f32x4 acc[4][4] = {};

    const char* Ab = (const char*)A;
    const char* Bb = (const char*)Bt;

    for (int k0 = 0; k0 < K; k0 += GBK) {
        __syncthreads();   // previous compute done with LDS

        #pragma unroll
        for (int j = 0; j < 4; ++j) {
            const int o   = wid * 4096 + j * 1024 + lane * 16;  // byte offset in 16 KB tile
            const int row = o >> 7;          // 128 B per row
            const int cb  = o & 127;
            gload_lds16(Ab + ((size_t)(m0 + row) * K + k0) * 2 + cb,
                        (char*)As + (wid * 4096 + j * 1024));
            gload_lds16(Bb + ((size_t)(n0 + row) * K + k0) * 2 + cb,
                        (char*)Bs + (wid * 4096 + j * 1024));
        }
        __syncthreads();   // barrier drains vmcnt -> tiles ready

        #pragma unroll
        for (int kk = 0; kk < 2; ++kk) {
            bf16x8 af[4];
            bf16x8 bfr[4];
            #pragma unroll
            for (int fm = 0; fm < 4; ++fm)
                af[fm] = *(const bf16x8*)&As[(wr * 64 + fm * 16 + l15) * GBK + l4 * 8 + kk * 32];
            #pragma unroll
            for (int fn = 0; fn < 4; ++fn)
                bfr[fn] = *(const bf16x8*)&Bs[(wc * 64 + fn * 16 + l15) * GBK + l4 * 8 + kk * 32];
            #pragma unroll
            for (int fm = 0; fm < 4; ++fm)
                #pragma unroll
                for (int fn = 0; fn < 4; ++fn)
                    acc[fm][fn] = __builtin_amdgcn_mfma_f32_16x16x32_bf16(
                        af[fm], bfr[fn], acc[fm][fn], 0, 0, 0);
        }
    }

    const int act = mode & 7;
    // C[m][n]: m = m0+wr*64+fm*16+l4*4+r, n = n0+wc*64+fn*16+l15
    #pragma unroll
    for (int fm = 0; fm < 4; ++fm) {
        #pragma unroll
        for (int r = 0; r < 4; ++r) {
            const int m = m0 + wr * 64 + fm * 16 + l4 * 4 + r;
            #pragma unroll
            for (int fn = 0; fn < 4; ++fn) {
                const int n = n0 + wc * 64 + fn * 16 + l15;
                float v = acc[fm][fn][r];
                if (bias) v += bias[n];
                if (act == ACT_SILU) {
                    v = v / (1.0f + expf(-v));
                } else if (act == ACT_GELU) {
                    v = 0.5f * v * (1.0f + erff(v * 0.70710678118654752f));
                }
                if (gmul)  v *= gmul[(size_t)m * N + n];
                if (resid) v += resid[(size_t)m * N + n];
                if (mode & OUT_BF16) ((unsigned short*)outp)[(size_t)m * N + n] = f2bf(v);
                else                 ((float*)outp)[(size_t)m * N + n] = v;
            }
        }
    }
}

// ---------------------------------------------------------------------------
// Tiled block-causal flash attention (fp32 VALU), bf16 output.
// ---------------------------------------------------------------------------
#define ATT_PAD 4
__global__ __launch_bounds__(256) void attn_kernel(const float* q, const float* k, const float* v, unsigned short* y) {
    __shared__ float Qt[HD][64 + ATT_PAD];
    __shared__ float Kt[HD][64 + ATT_PAD];
    __shared__ float Vs[64][HD + ATT_PAD];

    const int tid = threadIdx.x;
    const int tx = tid & 15;
    const int ty = tid >> 4;
    const int qt = blockIdx.x;
    const int h  = blockIdx.y;
    const int b  = blockIdx.z;
    const int i0 = qt * 64;
    const int qb = qt & 7;

    const size_t headoff = (size_t)b * T_SEQ * C_DIM + (size_t)h * HD;
    const float* qp = q + headoff;
    const float* kp = k + headoff;
    const float* vp = v + headoff;

    {
        const int jb4 = tx * 4;
        const int db4 = ty * 4;
        const float sc = 0.125f;
        float4 r0 = *reinterpret_cast<const float4*>(&qp[(size_t)(i0 + jb4 + 0) * C_DIM + db4]);
        float4 r1 = *reinterpret_cast<const float4*>(&qp[(size_t)(i0 + jb4 + 1) * C_DIM + db4]);
        float4 r2 = *reinterpret_cast<const float4*>(&qp[(size_t)(i0 + jb4 + 2) * C_DIM + db4]);
        float4 r3 = *reinterpret_cast<const float4*>(&qp[(size_t)(i0 + jb4 + 3) * C_DIM + db4]);
        *reinterpret_cast<float4*>(&Qt[db4 + 0][jb4]) = make_float4(r0.x*sc, r1.x*sc, r2.x*sc, r3.x*sc);
        *reinterpret_cast<float4*>(&Qt[db4 + 1][jb4]) = make_float4(r0.y*sc, r1.y*sc, r2.y*sc, r3.y*sc);
        *reinterpret_cast<float4*>(&Qt[db4 + 2][jb4]) = make_float4(r0.z*sc, r1.z*sc, r2.z*sc, r3.z*sc);
        *reinterpret_cast<float4*>(&Qt[db4 + 3][jb4]) = make_float4(r0.w*sc, r1.w*sc, r2.w*sc, r3.w*sc);
    }

    float o[4][4] = {};
    float m_run[4] = {-INFINITY, -INFINITY, -INFINITY, -INFINITY};
    float l_run[4] = {0.f, 0.f, 0.f, 0.f};

    for (int kb = 0; kb < 3; ++kb) {
        for (int jt = 0; jt <= qb; ++jt) {
            const int j0 = kb * TBLK + jt * 64;
            const bool masked = (jt == qb);

            __syncthreads();

            {
                const int jb4 = tx * 4;
                const int db4 = ty * 4;
                float4 r0 = *reinterpret_cast<const float4*>(&kp[(size_t)(j0 + jb4 + 0) * C_DIM + db4]);
                float4 r1 = *reinterpret_cast<const float4*>(&kp[(size_t)(j0 + jb4 + 1) * C_DIM + db4]);
                float4 r2 = *reinterpret_cast<const float4*>(&kp[(size_t)(j0 + jb4 + 2) * C_DIM + db4]);
                float4 r3 = *reinterpret_cast<const float4*>(&kp[(size_t)(j0 + jb4 + 3) * C_DIM + db4]);
                *reinterpret_cast<float4*>(&Kt[db4 + 0][jb4]) = make_float4(r0.x, r1.x, r2.x, r3.x);
                *reinterpret_cast<float4*>(&Kt[db4 + 1][jb4]) = make_float4(r0.y, r1.y, r2.y, r3.y);
                *reinterpret_cast<float4*>(&Kt[db4 + 2][jb4]) = make_float4(r0.z, r1.z, r2.z, r3.z);
                *reinterpret_cast<float4*>(&Kt[db4 + 3][jb4]) = make_float4(r0.w, r1.w, r2.w, r3.w);
                const int vc = tx * 4;
                #pragma unroll
                for (int l = 0; l < 4; ++l) {
                    const int r = ty + 16 * l;
                    *reinterpret_cast<float4*>(&Vs[r][vc]) =
                        *reinterpret_cast<const float4*>(&vp[(size_t)(j0 + r) * C_DIM + vc]);
                }
            }
            __syncthreads();

            float s[4][4] = {};
            #pragma unroll
            for (int d = 0; d < HD; ++d) {
                const float4 a  = *reinterpret_cast<const float4*>(&Qt[d][ty * 4]);
                const float4 bb = *reinterpret_cast<const float4*>(&Kt[d][tx * 4]);
                const float av[4] = {a.x, a.y, a.z, a.w};
                const float bv[4] = {bb.x, bb.y, bb.z, bb.w};
                #pragma unroll
                for (int i = 0; i < 4; ++i)
                    #pragma unroll
                    for (int j = 0; j < 4; ++j)
                        s[i][j] += av[i] * bv[j];
            }

            if (masked) {
                #pragma unroll
                for (int i = 0; i < 4; ++i)
                    #pragma unroll
                    for (int j = 0; j < 4; ++j)
                        if (tx * 4 + j > ty * 4 + i) s[i][j] = -INFINITY;
            }

            #pragma unroll
            for (int i = 0; i < 4; ++i) {
                float rm = fmaxf(fmaxf(s[i][0], s[i][1]), fmaxf(s[i][2], s[i][3]));
                #pragma unroll
                for (int off = 1; off < 16; off <<= 1) rm = fmaxf(rm, __shfl_xor(rm, off, 16));
                const float mn = fmaxf(m_run[i], rm);
                const float sc = expf(m_run[i] - mn);
                float rs = 0.f;
                #pragma unroll
                for (int j = 0; j < 4; ++j) {
                    const float pv = expf(s[i][j] - mn);
                    s[i][j] = pv;
                    rs += pv;
                }
                #pragma unroll
                for (int off = 1; off < 16; off <<= 1) rs += __shfl_xor(rs, off, 16);
                l_run[i] = l_run[i] * sc + rs;
                m_run[i] = mn;
                #pragma unroll
                for (int j = 0; j < 4; ++j) o[i][j] *= sc;
            }

            __syncthreads();

            *reinterpret_cast<float4*>(&Kt[tx * 4 + 0][ty * 4]) = make_float4(s[0][0], s[1][0], s[2][0], s[3][0]);
            *reinterpret_cast<float4*>(&Kt[tx * 4 + 1][ty * 4]) = make_float4(s[0][1], s[1][1], s[2][1], s[3][1]);
            *reinterpret_cast<float4*>(&Kt[tx * 4 + 2][ty * 4]) = make_float4(s[0][2], s[1][2], s[2][2], s[3][2]);
            *reinterpret_cast<float4*>(&Kt[tx * 4 + 3][ty * 4]) = make_float4(s[0][3], s[1][3], s[2][3], s[3][3]);

            __syncthreads();

            #pragma unroll
            for (int jj = 0; jj < 64; ++jj) {
                const float4 a  = *reinterpret_cast<const float4*>(&Kt[jj][ty * 4]);
                const float4 bb = *reinterpret_cast<const float4*>(&Vs[jj][tx * 4]);
                const float av[4] = {a.x, a.y, a.z, a.w};
                const float bv[4] = {bb.x, bb.y, bb.z, bb.w};
                #pragma unroll
                for (int i = 0; i < 4; ++i)
                    #pragma unroll
                    for (int j = 0; j < 4; ++j)
                        o[i][j] += av[i] * bv[j];
            }
        }
    }

    #pragma unroll
    for (int i = 0; i < 4; ++i) {
        const float inv = 1.0f / l_run[i];
        const int row = i0 + ty * 4 + i;
        ushort4 o4;
        o4.x = f2bf(o[i][0] * inv);
        o4.y = f2bf(o[i][1] * inv);
        o4.z = f2bf(o[i][2] * inv);
        o4.w = f2bf(o[i][3] * inv);
        *reinterpret_cast<ushort4*>(&y[headoff + (size_t)row * C_DIM + tx * 4]) = o4;
    }
}

// ---------------------------------------------------------------------------
// Launcher. Workspace (float units, U = 4,718,592 elems; 8U = 151 MB used).
// ---------------------------------------------------------------------------
extern "C" void kernel_launch(void* const* d_in, const int* in_sizes, int n_in,
                              void* d_out, int out_size, void* d_ws, size_t ws_size,
                              hipStream_t stream) {
    const float* x     = (const float*)d_in[0];
    const float* g1    = (const float*)d_in[1];
    const float* g2    = (const float*)d_in[2];
    const float* W_in  = (const float*)d_in[3];
    const float* b_in  = (const float*)d_in[4];
    const float* W_act = (const float*)d_in[5];
    const float* b_act = (const float*)d_in[6];
    const float* W_out = (const float*)d_in[7];
    const float* b_out = (const float*)d_in[8];
    const float* Wq    = (const float*)d_in[9];
    const float* bq    = (const float*)d_in[10];
    const float* Wk    = (const float*)d_in[11];
    const float* bk    = (const float*)d_in[12];
    const float* Wv    = (const float*)d_in[13];
    const float* bv    = (const float*)d_in[14];
    const float* Wp    = (const float*)d_in[15];
    const float* bp    = (const float*)d_in[16];
    const float* W1    = (const float*)d_in[17];
    const float* b1    = (const float*)d_in[18];
    const float* W2    = (const float*)d_in[19];
    const float* b2    = (const float*)d_in[20];
    float* out = (float*)d_out;

    // typed nulls (avoid std::nullptr_t at kernel-launch sites)
    const float* FNULL = 0;

    float* ws = (float*)d_ws;
    const size_t U = (size_t)M_ROWS * C_DIM;
    float* act_res = ws + 0 * U;
    float* qf      = ws + 1 * U;
    float* kf      = ws + 2 * U;
    float* vf      = ws + 3 * U;
    float* x1      = ws + 4 * U;
    unsigned short* y_bf  = (unsigned short*)(ws + 4 * U);
    unsigned short* h_bf  = (unsigned short*)(ws + 5 * U);
    unsigned short* u_bf  = h_bf + U;
    unsigned short* g_bf  = (unsigned short*)(ws + 6 * U);
    unsigned short* m_bf  = g_bf + U;
    unsigned short* a1_bf = (unsigned short*)(ws + 1 * U);
    unsigned short* wt    = (unsigned short*)(ws + 7 * U);

    const size_t WCC = (size_t)C_DIM * C_DIM;
    unsigned short* Wt_act = wt + 0 * WCC;
    unsigned short* Wt_in  = wt + 1 * WCC;
    unsigned short* Wtq    = wt + 2 * WCC;
    unsigned short* Wtk    = wt + 3 * WCC;
    unsigned short* Wtv    = wt + 4 * WCC;
    unsigned short* Wtp    = wt + 5 * WCC;
    unsigned short* Wt_out = wt + 6 * WCC;
    unsigned short* Wt1    = wt + 7 * WCC;                    // [3072][768]
    unsigned short* Wt2    = Wt1 + (size_t)C_DIM * 4 * C_DIM; // [768][3072]

    const dim3 tb(32, 8);
    const dim3 tg_cc(C_DIM / 32, C_DIM / 32);
    const dim3 tg_w1(4 * C_DIM / 32, C_DIM / 32);
    const dim3 tg_w2(C_DIM / 32, 4 * C_DIM / 32);

    wtrans_kernel<<<tg_cc, tb, 0, stream>>>(W_act, Wt_act, C_DIM, C_DIM);
    wtrans_kernel<<<tg_cc, tb, 0, stream>>>(W_in,  Wt_in,  C_DIM, C_DIM);
    wtrans_kernel<<<tg_cc, tb, 0, stream>>>(Wq,    Wtq,    C_DIM, C_DIM);
    wtrans_kernel<<<tg_cc, tb, 0, stream>>>(Wk,    Wtk,    C_DIM, C_DIM);
    wtrans_kernel<<<tg_cc, tb, 0, stream>>>(Wv,    Wtv,    C_DIM, C_DIM);
    wtrans_kernel<<<tg_cc, tb, 0, stream>>>(Wp,    Wtp,    C_DIM, C_DIM);
    wtrans_kernel<<<tg_cc, tb, 0, stream>>>(W_out, Wt_out, C_DIM, C_DIM);
    wtrans_kernel<<<tg_w1, tb, 0, stream>>>(W1,    Wt1,    C_DIM, 4 * C_DIM);
    wtrans_kernel<<<tg_w2, tb, 0, stream>>>(W2,    Wt2,    4 * C_DIM, C_DIM);

    const dim3 blk(256);
    const dim3 g_cc(M_ROWS / GBM, C_DIM / GBN);
    const dim3 g_c4(M_ROWS / GBM, 4 * C_DIM / GBN);
    const dim3 g_attn(T_SEQ / 64, NH, B_SZ);

    // h = rmsnorm(x, g1)
    rmsnorm_kernel<<<M_ROWS, blk, 0, stream>>>(x, g1, h_bf);
    // act_res = silu(h @ W_act + b_act) [f32]
    gemm_bf16<<<g_cc, blk, 0, stream>>>(h_bf, Wt_act, b_act, FNULL, FNULL,
                                        (void*)act_res, M_ROWS, C_DIM, C_DIM, ACT_SILU);
    // u = silu(h @ W_in + b_in) [bf16]
    gemm_bf16<<<g_cc, blk, 0, stream>>>(h_bf, Wt_in, b_in, FNULL, FNULL,
                                        (void*)u_bf, M_ROWS, C_DIM, C_DIM, ACT_SILU | OUT_BF16);
    // q, k, v [f32]
    gemm_bf16<<<g_cc, blk, 0, stream>>>(u_bf, Wtq, bq, FNULL, FNULL,
                                        (void*)qf, M_ROWS, C_DIM, C_DIM, ACT_NONE);
    gemm_bf16<<<g_cc, blk, 0, stream>>>(u_bf, Wtk, bk, FNULL, FNULL,
                                        (void*)kf, M_ROWS, C_DIM, C_DIM, ACT_NONE);
    gemm_bf16<<<g_cc, blk, 0, stream>>>(u_bf, Wtv, bv, FNULL, FNULL,
                                        (void*)vf, M_ROWS, C_DIM, C_DIM, ACT_NONE);
    // y = attention(q,k,v) [bf16]
    attn_kernel<<<g_attn, blk, 0, stream>>>(qf, kf, vf, y_bf);
    // g = (y @ Wp + bp) * act_res [bf16]
    gemm_bf16<<<g_cc, blk, 0, stream>>>(y_bf, Wtp, bp, act_res, FNULL,
                                        (void*)g_bf, M_ROWS, C_DIM, C_DIM, ACT_NONE | OUT_BF16);
    // x1 = x + g @ W_out + b_out [f32]
    gemm_bf16<<<g_cc, blk, 0, stream>>>(g_bf, Wt_out, b_out, FNULL, x,
                                        (void*)x1, M_ROWS, C_DIM, C_DIM, ACT_NONE);
    // m = rmsnorm(x1, g2) [bf16]
    rmsnorm_kernel<<<M_ROWS, blk, 0, stream>>>(x1, g2, m_bf);
    // a1 = gelu(m @ W1 + b1) [bf16]
    gemm_bf16<<<g_c4, blk, 0, stream>>>(m_bf, Wt1, b1, FNULL, FNULL,
                                        (void*)a1_bf, M_ROWS, 4 * C_DIM, C_DIM, ACT_GELU | OUT_BF16);
    // out = x1 + a1 @ W2 + b2 [f32]
    gemm_bf16<<<g_cc, blk, 0, stream>>>(a1_bf, Wt2, b2, FNULL, x1,
                                        (void*)out, M_ROWS, C_DIM, 4 * C_DIM, ACT_NONE);
}

// Round 6
// 806.590 us; speedup vs baseline: 9.0362x; 1.4555x over previous
//
#include <hip/hip_runtime.h>
#include <math.h>

// Problem constants (fixed by the reference)
#define B_SZ   4
#define T_SEQ  1536
#define C_DIM  768
#define NH     12
#define HD     64
#define TBLK   512
#define M_ROWS (B_SZ * T_SEQ)   // 6144

// epilogue mode: low 3 bits = activation, bit 3 = write bf16 (else f32)
#define ACT_NONE 0
#define ACT_SILU 1
#define ACT_GELU 2
#define OUT_BF16 8

typedef __attribute__((ext_vector_type(8))) short bf16x8;
typedef __attribute__((ext_vector_type(4))) float f32x4;

static __device__ __forceinline__ void gload_lds16(const void* g, void* l) {
    __builtin_amdgcn_global_load_lds(
        (const __attribute__((address_space(1))) void*)g,
        (__attribute__((address_space(3))) void*)l, 16, 0, 0);
}

// round-to-nearest-even f32 -> bf16 (bit pattern)
static __device__ __forceinline__ unsigned short f2bf(float f) {
    unsigned int u = __float_as_uint(f);
    u += 0x7fffu + ((u >> 16) & 1u);
    return (unsigned short)(u >> 16);
}

// ---------------------------------------------------------------------------
// Weight transpose + bf16 convert: W [K][N] f32 -> Wt [N][K] bf16
// ---------------------------------------------------------------------------
__global__ __launch_bounds__(256) void wtrans_kernel(const float* in, unsigned short* out, int K, int N) {
    __shared__ float t[32][33];
    const int tx = threadIdx.x, ty = threadIdx.y;
    const int n0 = blockIdx.x * 32, k0 = blockIdx.y * 32;
    #pragma unroll
    for (int j = 0; j < 4; ++j)
        t[ty + 8 * j][tx] = in[(size_t)(k0 + ty + 8 * j) * N + n0 + tx];
    __syncthreads();
    #pragma unroll
    for (int j = 0; j < 4; ++j)
        out[(size_t)(n0 + ty + 8 * j) * K + k0 + tx] = f2bf(t[tx][ty + 8 * j]);
}

// ---------------------------------------------------------------------------
// bf16 head-transpose: v_bf [B*T][C] -> vt [B*H*64][T]  (per head: [t][d]->[d][t])
// block (32,8), grid (T/32, HD/32, B*NH)
// ---------------------------------------------------------------------------
__global__ __launch_bounds__(256) void vtrans_kernel(const unsigned short* in, unsigned short* out) {
    __shared__ unsigned short t[32][33];
    const int tx = threadIdx.x, ty = threadIdx.y;
    const int t0 = blockIdx.x * 32;
    const int d0 = blockIdx.y * 32;
    const int z  = blockIdx.z;            // b*NH + h
    const int b  = z / NH, h = z % NH;
    #pragma unroll
    for (int j = 0; j < 4; ++j)
        t[ty + 8 * j][tx] = in[((size_t)b * T_SEQ + t0 + ty + 8 * j) * C_DIM + h * HD + d0 + tx];
    __syncthreads();
    #pragma unroll
    for (int j = 0; j < 4; ++j)
        out[((size_t)z * HD + d0 + ty + 8 * j) * T_SEQ + t0 + tx] = t[tx][ty + 8 * j];
}

// ---------------------------------------------------------------------------
// RMSNorm -> bf16 output
// ---------------------------------------------------------------------------
__global__ __launch_bounds__(256) void rmsnorm_kernel(const float* x, const float* g, unsigned short* out) {
    const int row = blockIdx.x;
    const int tid = threadIdx.x;
    const float* xr = x + (size_t)row * C_DIM;

    const float v0 = xr[tid];
    const float v1 = xr[tid + 256];
    const float v2 = xr[tid + 512];
    float ss = v0 * v0 + v1 * v1 + v2 * v2;

    #pragma unroll
    for (int off = 32; off > 0; off >>= 1) ss += __shfl_xor(ss, off, 64);
    __shared__ float s_red[4];
    if ((tid & 63) == 0) s_red[tid >> 6] = ss;
    __syncthreads();
    ss = s_red[0] + s_red[1] + s_red[2] + s_red[3];

    const float r = rsqrtf(ss * (1.0f / C_DIM) + 1e-6f);
    unsigned short* orow = out + (size_t)row * C_DIM;
    orow[tid]       = f2bf(v0 * r * g[tid]);
    orow[tid + 256] = f2bf(v1 * r * g[tid + 256]);
    orow[tid + 512] = f2bf(v2 * r * g[tid + 512]);
}

// ---------------------------------------------------------------------------
// bf16 MFMA GEMM (unchanged from R5): out = [resid +] ( act(A @ Bt^T + bias) [* gmul] )
// ---------------------------------------------------------------------------
#define GBM 128
#define GBN 128
#define GBK 64

__global__ __launch_bounds__(256) void gemm_bf16(const unsigned short* A, const unsigned short* Bt, const float* bias, const float* gmul, const float* resid, void* outp, int M, int N, int K, int mode) {
    __shared__ unsigned short As[GBM * GBK];
    __shared__ unsigned short Bs[GBN * GBK];

    const int tid  = threadIdx.x;
    const int lane = tid & 63;
    const int wid  = tid >> 6;
    const int wr   = wid >> 1;
    const int wc   = wid & 1;
    const int m0   = blockIdx.x * GBM;
    const int n0   = blockIdx.y * GBN;

    const int l15 = lane & 15;
    const int l4  = lane >> 4;

    f32x4 acc[4][4] = {};

    const char* Ab = (const char*)A;
    const char* Bb = (const char*)Bt;

    for (int k0 = 0; k0 < K; k0 += GBK) {
        __syncthreads();

        #pragma unroll
        for (int j = 0; j < 4; ++j) {
            const int o   = wid * 4096 + j * 1024 + lane * 16;
            const int row = o >> 7;
            const int cb  = o & 127;
            gload_lds16(Ab + ((size_t)(m0 + row) * K + k0) * 2 + cb,
                        (char*)As + (wid * 4096 + j * 1024));
            gload_lds16(Bb + ((size_t)(n0 + row) * K + k0) * 2 + cb,
                        (char*)Bs + (wid * 4096 + j * 1024));
        }
        __syncthreads();

        #pragma unroll
        for (int kk = 0; kk < 2; ++kk) {
            bf16x8 af[4];
            bf16x8 bfr[4];
            #pragma unroll
            for (int fm = 0; fm < 4; ++fm)
                af[fm] = *(const bf16x8*)&As[(wr * 64 + fm * 16 + l15) * GBK + l4 * 8 + kk * 32];
            #pragma unroll
            for (int fn = 0; fn < 4; ++fn)
                bfr[fn] = *(const bf16x8*)&Bs[(wc * 64 + fn * 16 + l15) * GBK + l4 * 8 + kk * 32];
            #pragma unroll
            for (int fm = 0; fm < 4; ++fm)
                #pragma unroll
                for (int fn = 0; fn < 4; ++fn)
                    acc[fm][fn] = __builtin_amdgcn_mfma_f32_16x16x32_bf16(
                        af[fm], bfr[fn], acc[fm][fn], 0, 0, 0);
        }
    }

    const int act = mode & 7;
    #pragma unroll
    for (int fm = 0; fm < 4; ++fm) {
        #pragma unroll
        for (int r = 0; r < 4; ++r) {
            const int m = m0 + wr * 64 + fm * 16 + l4 * 4 + r;
            #pragma unroll
            for (int fn = 0; fn < 4; ++fn) {
                const int n = n0 + wc * 64 + fn * 16 + l15;
                float v = acc[fm][fn][r];
                if (bias) v += bias[n];
                if (act == ACT_SILU) {
                    v = v / (1.0f + expf(-v));
                } else if (act == ACT_GELU) {
                    v = 0.5f * v * (1.0f + erff(v * 0.70710678118654752f));
                }
                if (gmul)  v *= gmul[(size_t)m * N + n];
                if (resid) v += resid[(size_t)m * N + n];
                if (mode & OUT_BF16) ((unsigned short*)outp)[(size_t)m * N + n] = f2bf(v);
                else                 ((float*)outp)[(size_t)m * N + n] = v;
            }
        }
    }
}

// ---------------------------------------------------------------------------
// MFMA block-causal flash attention (bf16 inputs, fp32 accum).
// One block = (b, h, 128-query tile); 4 waves, each owns 32 queries.
// K-tile = 64 keys. Per tile: S = Q K^T (16 MFMA/wave), wave-local online
// softmax, P -> LDS (bf16, padded pitch 72), O += P V (16 MFMA/wave).
// Qs/Ks/Vs staged via global_load_lds with PRE-SWIZZLED source cols
// (col16_src = (lane&7) ^ (row&7)); reads XOR the same pattern -> 8-way
// (= the b128 floor). Vt input is pre-transposed [b,h,d,t] in global.
// LDS: 16K + 8K + 8K + 18K = 50 KB -> 3 blocks/CU.
// ---------------------------------------------------------------------------
#define PPITCH 72

__global__ __launch_bounds__(256) void attn_mfma(const unsigned short* q, const unsigned short* k,
                                                 const unsigned short* vt, unsigned short* y) {
    __shared__ unsigned short Qs[128 * 64];
    __shared__ unsigned short Ks[64 * 64];
    __shared__ unsigned short Vs[64 * 64];     // V^T tile: [d][key]
    __shared__ unsigned short Pl[128 * PPITCH];

    const int tid  = threadIdx.x;
    const int lane = tid & 63;
    const int w    = tid >> 6;
    const int l15  = lane & 15;
    const int l4   = lane >> 4;
    const int qt   = blockIdx.x;          // 0..11
    const int h    = blockIdx.y;
    const int b    = blockIdx.z;
    const int i0   = qt * 128;
    const int qb   = qt & 3;              // q-tile pos within 512 block

    const size_t bT = (size_t)b * T_SEQ;
    const unsigned short* qp = q + bT * C_DIM + h * HD;
    const unsigned short* kp = k + bT * C_DIM + h * HD;
    const size_t vtb = (size_t)(b * NH + h) * HD * T_SEQ;

    const int lr   = lane >> 3;                     // row within 8-row chunk
    const int csrc = ((lane & 7) ^ lr) * 8;         // pre-swizzled src col (bf16)

    // stage Q (128 x 64), wave w rows [w*32, w*32+32)
    #pragma unroll
    for (int i = 0; i < 4; ++i) {
        const int row = w * 32 + i * 8 + lr;
        gload_lds16(qp + (size_t)(i0 + row) * C_DIM + csrc,
                    (char*)Qs + (w * 32 + i * 8) * 128);
    }

    f32x4 o[2][4] = {};
    float m_run[2][4], l_run[2][4];
    #pragma unroll
    for (int a = 0; a < 2; ++a)
        #pragma unroll
        for (int r = 0; r < 4; ++r) { m_run[a][r] = -INFINITY; l_run[a][r] = 0.f; }

    const int jt_max = 2 * qb + 1;
    for (int kb = 0; kb < 3; ++kb) {
        for (int jt = 0; jt <= jt_max; ++jt) {
            const int j0 = kb * TBLK + jt * 64;
            const bool diag = (jt >= 2 * qb);

            __syncthreads();   // prev PV done with Ks/Vs/Pl
            #pragma unroll
            for (int i = 0; i < 2; ++i) {
                const int row = w * 8 + i * 32 + lr;
                gload_lds16(kp + (size_t)(j0 + row) * C_DIM + csrc,
                            (char*)Ks + (w * 8 + i * 32) * 128);
                gload_lds16(vt + vtb + (size_t)row * T_SEQ + j0 + csrc,
                            (char*)Vs + (w * 8 + i * 32) * 128);
            }
            __syncthreads();   // drains vmcnt -> tiles ready

            // ---- S = Q K^T : per wave 32 q x 64 keys ----
            f32x4 s[2][4] = {};
            #pragma unroll
            for (int kk = 0; kk < 2; ++kk) {
                bf16x8 af[2], bfr[4];
                #pragma unroll
                for (int a = 0; a < 2; ++a)
                    af[a] = *(const bf16x8*)&Qs[(w * 32 + a * 16 + l15) * 64 + (((l4 + 4 * kk) ^ (l15 & 7)) * 8)];
                #pragma unroll
                for (int n = 0; n < 4; ++n)
                    bfr[n] = *(const bf16x8*)&Ks[(n * 16 + l15) * 64 + (((l4 + 4 * kk) ^ (l15 & 7)) * 8)];
                #pragma unroll
                for (int a = 0; a < 2; ++a)
                    #pragma unroll
                    for (int n = 0; n < 4; ++n)
                        s[a][n] = __builtin_amdgcn_mfma_f32_16x16x32_bf16(af[a], bfr[n], s[a][n], 0, 0, 0);
            }

            // ---- scale + mask + online softmax + P write ----
            #pragma unroll
            for (int a = 0; a < 2; ++a) {
                #pragma unroll
                for (int r = 0; r < 4; ++r) {
                    const int imod = qb * 128 + w * 32 + a * 16 + l4 * 4 + r;
                    float pv[4];
                    float rowm = -INFINITY;
                    #pragma unroll
                    for (int n = 0; n < 4; ++n) {
                        float sv = s[a][n][r] * 0.125f;
                        if (diag) {
                            const int jmod = jt * 64 + n * 16 + l15;
                            if (jmod > imod) sv = -INFINITY;
                        }
                        pv[n] = sv;
                        rowm = fmaxf(rowm, sv);
                    }
                    #pragma unroll
                    for (int off = 1; off < 16; off <<= 1) rowm = fmaxf(rowm, __shfl_xor(rowm, off, 64));
                    const float mn = fmaxf(m_run[a][r], rowm);
                    const float sc = __expf(m_run[a][r] - mn);   // 0 when m_run=-inf
                    float rs = 0.f;
                    #pragma unroll
                    for (int n = 0; n < 4; ++n) {
                        const float e = __expf(pv[n] - mn);      // masked -> 0
                        pv[n] = e;
                        rs += e;
                    }
                    #pragma unroll
                    for (int off = 1; off < 16; off <<= 1) rs += __shfl_xor(rs, off, 64);
                    l_run[a][r] = l_run[a][r] * sc + rs;
                    m_run[a][r] = mn;
                    const int qrow = w * 32 + a * 16 + l4 * 4 + r;
                    #pragma unroll
                    for (int n = 0; n < 4; ++n) {
                        o[a][n][r] *= sc;
                        Pl[qrow * PPITCH + n * 16 + l15] = f2bf(pv[n]);
                    }
                }
            }
            __syncthreads();   // P visible

            // ---- O += P V : A = Pl[q][k], B = Vs[d][k] ----
            #pragma unroll
            for (int kk = 0; kk < 2; ++kk) {
                bf16x8 af[2], bfr[4];
                #pragma unroll
                for (int a = 0; a < 2; ++a)
                    af[a] = *(const bf16x8*)&Pl[(w * 32 + a * 16 + l15) * PPITCH + l4 * 8 + kk * 32];
                #pragma unroll
                for (int n = 0; n < 4; ++n)
                    bfr[n] = *(const bf16x8*)&Vs[(n * 16 + l15) * 64 + (((l4 + 4 * kk) ^ (l15 & 7)) * 8)];
                #pragma unroll
                for (int a = 0; a < 2; ++a)
                    #pragma unroll
                    for (int n = 0; n < 4; ++n)
                        o[a][n] = __builtin_amdgcn_mfma_f32_16x16x32_bf16(af[a], bfr[n], o[a][n], 0, 0, 0);
            }
        }
    }

    // ---- normalize + store (bf16) ----
    unsigned short* yp = y + (bT + i0) * C_DIM + h * HD;
    #pragma unroll
    for (int a = 0; a < 2; ++a) {
        #pragma unroll
        for (int r = 0; r < 4; ++r) {
            const int qq = w * 32 + a * 16 + l4 * 4 + r;
            const float inv = 1.0f / l_run[a][r];
            #pragma unroll
            for (int n = 0; n < 4; ++n)
                yp[(size_t)qq * C_DIM + n * 16 + l15] = f2bf(o[a][n][r] * inv);
        }
    }
}

// ---------------------------------------------------------------------------
// Launcher. Workspace in float units U = 6144*768 = 4,718,592 (~18.9 MB):
//  f32:  act_res [0,1U) | x1 [2U,3U)
//  bf16 (ushort* wsb, offsets in bf16 units):
//   h_bf/y_bf @2U | u_bf/g_bf @3U | q_bf @4U | k_bf @5U | v_bf/m_bf @6U
//   vt_bf @7U | a1_bf @7U..11U (after vt dead) | weights @11U..~12.9U
//  total ~6.5U floats = 123 MB.
// ---------------------------------------------------------------------------
extern "C" void kernel_launch(void* const* d_in, const int* in_sizes, int n_in,
                              void* d_out, int out_size, void* d_ws, size_t ws_size,
                              hipStream_t stream) {
    const float* x     = (const float*)d_in[0];
    const float* g1    = (const float*)d_in[1];
    const float* g2    = (const float*)d_in[2];
    const float* W_in  = (const float*)d_in[3];
    const float* b_in  = (const float*)d_in[4];
    const float* W_act = (const float*)d_in[5];
    const float* b_act = (const float*)d_in[6];
    const float* W_out = (const float*)d_in[7];
    const float* b_out = (const float*)d_in[8];
    const float* Wq    = (const float*)d_in[9];
    const float* bq    = (const float*)d_in[10];
    const float* Wk    = (const float*)d_in[11];
    const float* bk    = (const float*)d_in[12];
    const float* Wv    = (const float*)d_in[13];
    const float* bv    = (const float*)d_in[14];
    const float* Wp    = (const float*)d_in[15];
    const float* bp    = (const float*)d_in[16];
    const float* W1    = (const float*)d_in[17];
    const float* b1    = (const float*)d_in[18];
    const float* W2    = (const float*)d_in[19];
    const float* b2    = (const float*)d_in[20];
    float* out = (float*)d_out;

    const float* FNULL = 0;

    float* ws = (float*)d_ws;
    unsigned short* wsb = (unsigned short*)d_ws;
    const size_t U = (size_t)M_ROWS * C_DIM;

    float* act_res = ws;                       // [0,1U) f32
    unsigned short* h_bf  = wsb + 2 * U;       // [1.0U,1.5U)
    unsigned short* u_bf  = wsb + 3 * U;       // [1.5U,2.0U)
    unsigned short* q_bf  = wsb + 4 * U;       // [2.0U,2.5U)
    unsigned short* k_bf  = wsb + 5 * U;       // [2.5U,3.0U)
    unsigned short* v_bf  = wsb + 6 * U;       // [3.0U,3.5U)
    unsigned short* vt_bf = wsb + 7 * U;       // [3.5U,4.0U)
    unsigned short* y_bf  = wsb + 2 * U;       // reuse h (dead after u GEMM)
    unsigned short* g_bf  = wsb + 3 * U;       // reuse u (dead after v GEMM)
    float*          x1    = ws  + 2 * U;       // reuse q,k (dead after attn)
    unsigned short* m_bf  = wsb + 6 * U;       // reuse v (dead after vtrans)
    unsigned short* a1_bf = wsb + 7 * U;       // [3.5U,5.5U) (vt dead after attn)
    unsigned short* wt    = wsb + 11 * U;      // weights, ~1.9U bf16

    const size_t WCC = (size_t)C_DIM * C_DIM;
    unsigned short* Wt_act = wt + 0 * WCC;
    unsigned short* Wt_in  = wt + 1 * WCC;
    unsigned short* Wtq    = wt + 2 * WCC;
    unsigned short* Wtk    = wt + 3 * WCC;
    unsigned short* Wtv    = wt + 4 * WCC;
    unsigned short* Wtp    = wt + 5 * WCC;
    unsigned short* Wt_out = wt + 6 * WCC;
    unsigned short* Wt1    = wt + 7 * WCC;                    // [3072][768]
    unsigned short* Wt2    = Wt1 + (size_t)C_DIM * 4 * C_DIM; // [768][3072]

    const dim3 tb(32, 8);
    const dim3 tg_cc(C_DIM / 32, C_DIM / 32);
    const dim3 tg_w1(4 * C_DIM / 32, C_DIM / 32);
    const dim3 tg_w2(C_DIM / 32, 4 * C_DIM / 32);

    wtrans_kernel<<<tg_cc, tb, 0, stream>>>(W_act, Wt_act, C_DIM, C_DIM);
    wtrans_kernel<<<tg_cc, tb, 0, stream>>>(W_in,  Wt_in,  C_DIM, C_DIM);
    wtrans_kernel<<<tg_cc, tb, 0, stream>>>(Wq,    Wtq,    C_DIM, C_DIM);
    wtrans_kernel<<<tg_cc, tb, 0, stream>>>(Wk,    Wtk,    C_DIM, C_DIM);
    wtrans_kernel<<<tg_cc, tb, 0, stream>>>(Wv,    Wtv,    C_DIM, C_DIM);
    wtrans_kernel<<<tg_cc, tb, 0, stream>>>(Wp,    Wtp,    C_DIM, C_DIM);
    wtrans_kernel<<<tg_cc, tb, 0, stream>>>(W_out, Wt_out, C_DIM, C_DIM);
    wtrans_kernel<<<tg_w1, tb, 0, stream>>>(W1,    Wt1,    C_DIM, 4 * C_DIM);
    wtrans_kernel<<<tg_w2, tb, 0, stream>>>(W2,    Wt2,    4 * C_DIM, C_DIM);

    const dim3 blk(256);
    const dim3 g_cc(M_ROWS / GBM, C_DIM / GBN);
    const dim3 g_c4(M_ROWS / GBM, 4 * C_DIM / GBN);
    const dim3 g_vt(T_SEQ / 32, HD / 32, B_SZ * NH);
    const dim3 g_attn(T_SEQ / 128, NH, B_SZ);

    // h = rmsnorm(x, g1)
    rmsnorm_kernel<<<M_ROWS, blk, 0, stream>>>(x, g1, h_bf);
    // act_res = silu(h @ W_act + b_act) [f32]
    gemm_bf16<<<g_cc, blk, 0, stream>>>(h_bf, Wt_act, b_act, FNULL, FNULL,
                                        (void*)act_res, M_ROWS, C_DIM, C_DIM, ACT_SILU);
    // u = silu(h @ W_in + b_in) [bf16]
    gemm_bf16<<<g_cc, blk, 0, stream>>>(h_bf, Wt_in, b_in, FNULL, FNULL,
                                        (void*)u_bf, M_ROWS, C_DIM, C_DIM, ACT_SILU | OUT_BF16);
    // q, k, v [bf16]
    gemm_bf16<<<g_cc, blk, 0, stream>>>(u_bf, Wtq, bq, FNULL, FNULL,
                                        (void*)q_bf, M_ROWS, C_DIM, C_DIM, ACT_NONE | OUT_BF16);
    gemm_bf16<<<g_cc, blk, 0, stream>>>(u_bf, Wtk, bk, FNULL, FNULL,
                                        (void*)k_bf, M_ROWS, C_DIM, C_DIM, ACT_NONE | OUT_BF16);
    gemm_bf16<<<g_cc, blk, 0, stream>>>(u_bf, Wtv, bv, FNULL, FNULL,
                                        (void*)v_bf, M_ROWS, C_DIM, C_DIM, ACT_NONE | OUT_BF16);
    // vt = head-transpose(v)
    vtrans_kernel<<<g_vt, tb, 0, stream>>>(v_bf, vt_bf);
    // y = attention(q, k, vt) [bf16]
    attn_mfma<<<g_attn, blk, 0, stream>>>(q_bf, k_bf, vt_bf, y_bf);
    // g = (y @ Wp + bp) * act_res [bf16]
    gemm_bf16<<<g_cc, blk, 0, stream>>>(y_bf, Wtp, bp, act_res, FNULL,
                                        (void*)g_bf, M_ROWS, C_DIM, C_DIM, ACT_NONE | OUT_BF16);
    // x1 = x + g @ W_out + b_out [f32]
    gemm_bf16<<<g_cc, blk, 0, stream>>>(g_bf, Wt_out, b_out, FNULL, x,
                                        (void*)x1, M_ROWS, C_DIM, C_DIM, ACT_NONE);
    // m = rmsnorm(x1, g2) [bf16]
    rmsnorm_kernel<<<M_ROWS, blk, 0, stream>>>(x1, g2, m_bf);
    // a1 = gelu(m @ W1 + b1) [bf16]
    gemm_bf16<<<g_c4, blk, 0, stream>>>(m_bf, Wt1, b1, FNULL, FNULL,
                                        (void*)a1_bf, M_ROWS, 4 * C_DIM, C_DIM, ACT_GELU | OUT_BF16);
    // out = x1 + a1 @ W2 + b2 [f32]
    gemm_bf16<<<g_cc, blk, 0, stream>>>(a1_bf, Wt2, b2, FNULL, x1,
                                        (void*)out, M_ROWS, C_DIM, 4 * C_DIM, ACT_NONE);
}

// Round 7
// 729.005 us; speedup vs baseline: 9.9979x; 1.1064x over previous
//
#include <hip/hip_runtime.h>
#include <math.h>

// Problem constants (fixed by the reference)
#define B_SZ   4
#define T_SEQ  1536
#define C_DIM  768
#define QKVC   (3 * C_DIM)      // 2304
#define NH     12
#define HD     64
#define TBLK   512
#define M_ROWS (B_SZ * T_SEQ)   // 6144

// epilogue mode: low 3 bits = activation, bit 3 = bf16 out, bit 4 = dual-out
#define ACT_NONE 0
#define ACT_SILU 1
#define ACT_GELU 2
#define OUT_BF16 8
#define OUT_DUAL 16

typedef __attribute__((ext_vector_type(8))) short bf16x8;
typedef __attribute__((ext_vector_type(4))) float f32x4;

static __device__ __forceinline__ void gload_lds16(const void* g, void* l) {
    __builtin_amdgcn_global_load_lds(
        (const __attribute__((address_space(1))) void*)g,
        (__attribute__((address_space(3))) void*)l, 16, 0, 0);
}

// round-to-nearest-even f32 -> bf16 (bit pattern)
static __device__ __forceinline__ unsigned short f2bf(float f) {
    unsigned int u = __float_as_uint(f);
    u += 0x7fffu + ((u >> 16) & 1u);
    return (unsigned short)(u >> 16);
}

// ---------------------------------------------------------------------------
// Fused weight transpose for the 7 CxC weights: W [768][768] f32 -> Wt [768][768] bf16
// grid (24, 24, 7); z selects source; dst = wt + z*WCC
// ---------------------------------------------------------------------------
struct WPtrs { const float* p[7]; };

__global__ __launch_bounds__(256) void wtrans7_kernel(WPtrs w, unsigned short* out) {
    __shared__ float t[32][33];
    const int tx = threadIdx.x, ty = threadIdx.y;
    const int n0 = blockIdx.x * 32, k0 = blockIdx.y * 32;
    const float* in = w.p[blockIdx.z];
    unsigned short* o = out + (size_t)blockIdx.z * C_DIM * C_DIM;
    #pragma unroll
    for (int j = 0; j < 4; ++j)
        t[ty + 8 * j][tx] = in[(size_t)(k0 + ty + 8 * j) * C_DIM + n0 + tx];
    __syncthreads();
    #pragma unroll
    for (int j = 0; j < 4; ++j)
        o[(size_t)(n0 + ty + 8 * j) * C_DIM + k0 + tx] = f2bf(t[tx][ty + 8 * j]);
}

// generic single-weight transpose (for W1, W2)
__global__ __launch_bounds__(256) void wtrans_kernel(const float* in, unsigned short* out, int K, int N) {
    __shared__ float t[32][33];
    const int tx = threadIdx.x, ty = threadIdx.y;
    const int n0 = blockIdx.x * 32, k0 = blockIdx.y * 32;
    #pragma unroll
    for (int j = 0; j < 4; ++j)
        t[ty + 8 * j][tx] = in[(size_t)(k0 + ty + 8 * j) * N + n0 + tx];
    __syncthreads();
    #pragma unroll
    for (int j = 0; j < 4; ++j)
        out[(size_t)(n0 + ty + 8 * j) * K + k0 + tx] = f2bf(t[tx][ty + 8 * j]);
}

// ---------------------------------------------------------------------------
// Bias concat: qkvb[2304] = bq|bk|bv ; actb[1536] = b_act|b_in
// ---------------------------------------------------------------------------
__global__ __launch_bounds__(256) void biascat_kernel(const float* bq, const float* bk, const float* bv,
                                                      const float* ba, const float* bi,
                                                      float* qkvb, float* actb) {
    const int i = blockIdx.x * 256 + threadIdx.x;
    if (i < 2304) qkvb[i] = (i < 768) ? bq[i] : ((i < 1536) ? bk[i - 768] : bv[i - 1536]);
    if (i < 1536) actb[i] = (i < 768) ? ba[i] : bi[i - 768];
}

// ---------------------------------------------------------------------------
// bf16 head-transpose of V (from fused qkv): qkv [B*T][2304] -> vt [B*H*64][T]
// ---------------------------------------------------------------------------
__global__ __launch_bounds__(256) void vtrans_kernel(const unsigned short* in, unsigned short* out) {
    __shared__ unsigned short t[32][33];
    const int tx = threadIdx.x, ty = threadIdx.y;
    const int t0 = blockIdx.x * 32;
    const int d0 = blockIdx.y * 32;
    const int z  = blockIdx.z;            // b*NH + h
    const int b  = z / NH, h = z % NH;
    #pragma unroll
    for (int j = 0; j < 4; ++j)
        t[ty + 8 * j][tx] = in[((size_t)b * T_SEQ + t0 + ty + 8 * j) * QKVC + 2 * C_DIM + h * HD + d0 + tx];
    __syncthreads();
    #pragma unroll
    for (int j = 0; j < 4; ++j)
        out[((size_t)z * HD + d0 + ty + 8 * j) * T_SEQ + t0 + tx] = t[tx][ty + 8 * j];
}

// ---------------------------------------------------------------------------
// RMSNorm -> bf16 output
// ---------------------------------------------------------------------------
__global__ __launch_bounds__(256) void rmsnorm_kernel(const float* x, const float* g, unsigned short* out) {
    const int row = blockIdx.x;
    const int tid = threadIdx.x;
    const float* xr = x + (size_t)row * C_DIM;

    const float v0 = xr[tid];
    const float v1 = xr[tid + 256];
    const float v2 = xr[tid + 512];
    float ss = v0 * v0 + v1 * v1 + v2 * v2;

    #pragma unroll
    for (int off = 32; off > 0; off >>= 1) ss += __shfl_xor(ss, off, 64);
    __shared__ float s_red[4];
    if ((tid & 63) == 0) s_red[tid >> 6] = ss;
    __syncthreads();
    ss = s_red[0] + s_red[1] + s_red[2] + s_red[3];

    const float r = rsqrtf(ss * (1.0f / C_DIM) + 1e-6f);
    unsigned short* orow = out + (size_t)row * C_DIM;
    orow[tid]       = f2bf(v0 * r * g[tid]);
    orow[tid + 256] = f2bf(v1 * r * g[tid + 256]);
    orow[tid + 512] = f2bf(v2 * r * g[tid + 512]);
}

// ---------------------------------------------------------------------------
// bf16 MFMA GEMM, double-buffered prefetch pipeline + XOR-swizzled LDS.
//   out = [resid +] ( act(A @ Bt^T + bias) [* gmul] )       (normal modes)
//   OUT_DUAL: cols <768 -> f32 via gmul arg; cols >=768 -> bf16 via outp
// Tile 128x128, BK=64, 4 waves (2x2). LDS 2x32 KB (dbuf).
// Pipeline per K-step: STAGE(next) ; vmcnt(8) ; barrier ; MFMA(cur) ;
// lgkmcnt(0) ; barrier.  Loads for tile t+1 stay in flight across compute.
// Swizzle (both-sides, m201 pattern): source 16B-group (lane&7)^(lane>>3),
// linear LDS dest; read group (l4+4kk)^(row&7) -> 16-way conflict -> 2-way.
// ---------------------------------------------------------------------------
#define GBM 128
#define GBN 128
#define GBK 64
#define TILE_SH (GBM * GBK)

__global__ __launch_bounds__(256) void gemm_bf16(const unsigned short* A, const unsigned short* Bt, const float* bias, const float* gmul, const float* resid, void* outp, int M, int N, int K, int mode) {
    __shared__ unsigned short As[2][TILE_SH];
    __shared__ unsigned short Bs[2][TILE_SH];

    const int tid  = threadIdx.x;
    const int lane = tid & 63;
    const int wid  = tid >> 6;
    const int wr   = wid >> 1;
    const int wc   = wid & 1;
    const int m0   = blockIdx.x * GBM;
    const int n0   = blockIdx.y * GBN;

    const int l15 = lane & 15;
    const int l4  = lane >> 4;

    const int csw  = (((lane & 7) ^ (lane >> 3)) << 4);   // swizzled source byte col
    const int lrow = (lane >> 3);                         // source row within 8-chunk

    f32x4 acc[4][4] = {};

    const char* Ab = (const char*)A;
    const char* Bb = (const char*)Bt;

    // stage one K-tile into buffer `buf` (8 gload_lds / thread)
    auto stage = [&](int buf, int k0) {
        char* Ad = (char*)&As[buf][0];
        char* Bd = (char*)&Bs[buf][0];
        #pragma unroll
        for (int j = 0; j < 4; ++j) {
            const int base = wid * 4096 + j * 1024;       // byte base of 8-row chunk
            const int row  = (base >> 7) + lrow;          // tile row for THIS lane
            gload_lds16(Ab + ((size_t)(m0 + row) * K + k0) * 2 + csw, Ad + base);
            gload_lds16(Bb + ((size_t)(n0 + row) * K + k0) * 2 + csw, Bd + base);
        }
    };

    stage(0, 0);
    int cur = 0;
    for (int k0 = 0; k0 < K; k0 += GBK) {
        if (k0 + GBK < K) {
            stage(cur ^ 1, k0 + GBK);
            asm volatile("s_waitcnt vmcnt(8)" ::: "memory");   // cur tile landed; next in flight
        } else {
            asm volatile("s_waitcnt vmcnt(0)" ::: "memory");
        }
        __builtin_amdgcn_s_barrier();
        __builtin_amdgcn_sched_barrier(0);

        const unsigned short* Ac = &As[cur][0];
        const unsigned short* Bc = &Bs[cur][0];
        #pragma unroll
        for (int kk = 0; kk < 2; ++kk) {
            bf16x8 af[4], bfr[4];
            const int g = l4 + 4 * kk;
            #pragma unroll
            for (int fm = 0; fm < 4; ++fm)
                af[fm] = *(const bf16x8*)&Ac[(wr * 64 + fm * 16 + l15) * GBK + ((g ^ (l15 & 7)) * 8)];
            #pragma unroll
            for (int fn = 0; fn < 4; ++fn)
                bfr[fn] = *(const bf16x8*)&Bc[(wc * 64 + fn * 16 + l15) * GBK + ((g ^ (l15 & 7)) * 8)];
            #pragma unroll
            for (int fm = 0; fm < 4; ++fm)
                #pragma unroll
                for (int fn = 0; fn < 4; ++fn)
                    acc[fm][fn] = __builtin_amdgcn_mfma_f32_16x16x32_bf16(
                        af[fm], bfr[fn], acc[fm][fn], 0, 0, 0);
        }

        asm volatile("s_waitcnt lgkmcnt(0)" ::: "memory");     // ds_reads done before reuse
        __builtin_amdgcn_s_barrier();
        cur ^= 1;
    }

    const int act = mode & 7;
    #pragma unroll
    for (int fm = 0; fm < 4; ++fm) {
        #pragma unroll
        for (int r = 0; r < 4; ++r) {
            const int m = m0 + wr * 64 + fm * 16 + l4 * 4 + r;
            #pragma unroll
            for (int fn = 0; fn < 4; ++fn) {
                const int n = n0 + wc * 64 + fn * 16 + l15;
                float v = acc[fm][fn][r];
                if (bias) v += bias[n];
                if (act == ACT_SILU) {
                    v = v / (1.0f + expf(-v));
                } else if (act == ACT_GELU) {
                    v = 0.5f * v * (1.0f + erff(v * 0.70710678118654752f));
                }
                if (mode & OUT_DUAL) {
                    if (n < 768) ((float*)gmul)[(size_t)m * 768 + n] = v;
                    else ((unsigned short*)outp)[(size_t)m * 768 + (n - 768)] = f2bf(v);
                } else {
                    if (gmul)  v *= gmul[(size_t)m * N + n];
                    if (resid) v += resid[(size_t)m * N + n];
                    if (mode & OUT_BF16) ((unsigned short*)outp)[(size_t)m * N + n] = f2bf(v);
                    else                 ((float*)outp)[(size_t)m * N + n] = v;
                }
            }
        }
    }
}

// ---------------------------------------------------------------------------
// MFMA block-causal flash attention (unchanged structure from R6; reads the
// fused qkv buffer with row stride QKVC; y written bf16 stride C_DIM).
// ---------------------------------------------------------------------------
#define PPITCH 72

__global__ __launch_bounds__(256) void attn_mfma(const unsigned short* qkv,
                                                 const unsigned short* vt, unsigned short* y) {
    __shared__ unsigned short Qs[128 * 64];
    __shared__ unsigned short Ks[64 * 64];
    __shared__ unsigned short Vs[64 * 64];     // V^T tile: [d][key]
    __shared__ unsigned short Pl[128 * PPITCH];

    const int tid  = threadIdx.x;
    const int lane = tid & 63;
    const int w    = tid >> 6;
    const int l15  = lane & 15;
    const int l4   = lane >> 4;
    const int qt   = blockIdx.x;
    const int h    = blockIdx.y;
    const int b    = blockIdx.z;
    const int i0   = qt * 128;
    const int qb   = qt & 3;

    const size_t bT = (size_t)b * T_SEQ;
    const unsigned short* qp = qkv + bT * QKVC + h * HD;
    const unsigned short* kp = qkv + bT * QKVC + C_DIM + h * HD;
    const size_t vtb = (size_t)(b * NH + h) * HD * T_SEQ;

    const int lr   = lane >> 3;
    const int csrc = ((lane & 7) ^ lr) * 8;

    #pragma unroll
    for (int i = 0; i < 4; ++i) {
        const int row = w * 32 + i * 8 + lr;
        gload_lds16(qp + (size_t)(i0 + row) * QKVC + csrc,
                    (char*)Qs + (w * 32 + i * 8) * 128);
    }

    f32x4 o[2][4] = {};
    float m_run[2][4], l_run[2][4];
    #pragma unroll
    for (int a = 0; a < 2; ++a)
        #pragma unroll
        for (int r = 0; r < 4; ++r) { m_run[a][r] = -INFINITY; l_run[a][r] = 0.f; }

    const int jt_max = 2 * qb + 1;
    for (int kb = 0; kb < 3; ++kb) {
        for (int jt = 0; jt <= jt_max; ++jt) {
            const int j0 = kb * TBLK + jt * 64;
            const bool diag = (jt >= 2 * qb);

            __syncthreads();
            #pragma unroll
            for (int i = 0; i < 2; ++i) {
                const int row = w * 8 + i * 32 + lr;
                gload_lds16(kp + (size_t)(j0 + row) * QKVC + csrc,
                            (char*)Ks + (w * 8 + i * 32) * 128);
                gload_lds16(vt + vtb + (size_t)row * T_SEQ + j0 + csrc,
                            (char*)Vs + (w * 8 + i * 32) * 128);
            }
            __syncthreads();

            f32x4 s[2][4] = {};
            #pragma unroll
            for (int kk = 0; kk < 2; ++kk) {
                bf16x8 af[2], bfr[4];
                #pragma unroll
                for (int a = 0; a < 2; ++a)
                    af[a] = *(const bf16x8*)&Qs[(w * 32 + a * 16 + l15) * 64 + (((l4 + 4 * kk) ^ (l15 & 7)) * 8)];
                #pragma unroll
                for (int n = 0; n < 4; ++n)
                    bfr[n] = *(const bf16x8*)&Ks[(n * 16 + l15) * 64 + (((l4 + 4 * kk) ^ (l15 & 7)) * 8)];
                #pragma unroll
                for (int a = 0; a < 2; ++a)
                    #pragma unroll
                    for (int n = 0; n < 4; ++n)
                        s[a][n] = __builtin_amdgcn_mfma_f32_16x16x32_bf16(af[a], bfr[n], s[a][n], 0, 0, 0);
            }

            #pragma unroll
            for (int a = 0; a < 2; ++a) {
                #pragma unroll
                for (int r = 0; r < 4; ++r) {
                    const int imod = qb * 128 + w * 32 + a * 16 + l4 * 4 + r;
                    float pv[4];
                    float rowm = -INFINITY;
                    #pragma unroll
                    for (int n = 0; n < 4; ++n) {
                        float sv = s[a][n][r] * 0.125f;
                        if (diag) {
                            const int jmod = jt * 64 + n * 16 + l15;
                            if (jmod > imod) sv = -INFINITY;
                        }
                        pv[n] = sv;
                        rowm = fmaxf(rowm, sv);
                    }
                    #pragma unroll
                    for (int off = 1; off < 16; off <<= 1) rowm = fmaxf(rowm, __shfl_xor(rowm, off, 64));
                    const float mn = fmaxf(m_run[a][r], rowm);
                    const float sc = __expf(m_run[a][r] - mn);
                    float rs = 0.f;
                    #pragma unroll
                    for (int n = 0; n < 4; ++n) {
                        const float e = __expf(pv[n] - mn);
                        pv[n] = e;
                        rs += e;
                    }
                    #pragma unroll
                    for (int off = 1; off < 16; off <<= 1) rs += __shfl_xor(rs, off, 64);
                    l_run[a][r] = l_run[a][r] * sc + rs;
                    m_run[a][r] = mn;
                    const int qrow = w * 32 + a * 16 + l4 * 4 + r;
                    #pragma unroll
                    for (int n = 0; n < 4; ++n) {
                        o[a][n][r] *= sc;
                        Pl[qrow * PPITCH + n * 16 + l15] = f2bf(pv[n]);
                    }
                }
            }
            __syncthreads();

            #pragma unroll
            for (int kk = 0; kk < 2; ++kk) {
                bf16x8 af[2], bfr[4];
                #pragma unroll
                for (int a = 0; a < 2; ++a)
                    af[a] = *(const bf16x8*)&Pl[(w * 32 + a * 16 + l15) * PPITCH + l4 * 8 + kk * 32];
                #pragma unroll
                for (int n = 0; n < 4; ++n)
                    bfr[n] = *(const bf16x8*)&Vs[(n * 16 + l15) * 64 + (((l4 + 4 * kk) ^ (l15 & 7)) * 8)];
                #pragma unroll
                for (int a = 0; a < 2; ++a)
                    #pragma unroll
                    for (int n = 0; n < 4; ++n)
                        o[a][n] = __builtin_amdgcn_mfma_f32_16x16x32_bf16(af[a], bfr[n], o[a][n], 0, 0, 0);
            }
        }
    }

    unsigned short* yp = y + (bT + i0) * C_DIM + h * HD;
    #pragma unroll
    for (int a = 0; a < 2; ++a) {
        #pragma unroll
        for (int r = 0; r < 4; ++r) {
            const int qq = w * 32 + a * 16 + l4 * 4 + r;
            const float inv = 1.0f / l_run[a][r];
            #pragma unroll
            for (int n = 0; n < 4; ++n)
                yp[(size_t)qq * C_DIM + n * 16 + l15] = f2bf(o[a][n][r] * inv);
        }
    }
}

// ---------------------------------------------------------------------------
// Launcher. Workspace (float units U = 4,718,592; footprint ~6.5U = 123 MB):
//  [0,1U)     bf16 weights (0.94U) + qkvb/actb f32 (at float idx 4.50M/4.505M)
//  [1U,2U)    act_res f32
//  [2U,2.5U)  h_bf -> y_bf      [2.5U,3U) u_bf -> g_bf
//  [3U,4.5U)  qkv_bf;  x1 f32 reuses [3U,4U), m_bf reuses [4U,4.5U) after attn
//  [4.5U,5U)  vt_bf;   a1_bf reuses [4.5U,6.5U) after attn
// ---------------------------------------------------------------------------
extern "C" void kernel_launch(void* const* d_in, const int* in_sizes, int n_in,
                              void* d_out, int out_size, void* d_ws, size_t ws_size,
                              hipStream_t stream) {
    const float* x     = (const float*)d_in[0];
    const float* g1    = (const float*)d_in[1];
    const float* g2    = (const float*)d_in[2];
    const float* W_in  = (const float*)d_in[3];
    const float* b_in  = (const float*)d_in[4];
    const float* W_act = (const float*)d_in[5];
    const float* b_act = (const float*)d_in[6];
    const float* W_out = (const float*)d_in[7];
    const float* b_out = (const float*)d_in[8];
    const float* Wq    = (const float*)d_in[9];
    const float* bq    = (const float*)d_in[10];
    const float* Wk    = (const float*)d_in[11];
    const float* bk    = (const float*)d_in[12];
    const float* Wv    = (const float*)d_in[13];
    const float* bv    = (const float*)d_in[14];
    const float* Wp    = (const float*)d_in[15];
    const float* bp    = (const float*)d_in[16];
    const float* W1    = (const float*)d_in[17];
    const float* b1    = (const float*)d_in[18];
    const float* W2    = (const float*)d_in[19];
    const float* b2    = (const float*)d_in[20];
    float* out = (float*)d_out;

    const float* FNULL = 0;

    float* ws = (float*)d_ws;
    unsigned short* wsb = (unsigned short*)d_ws;
    const size_t U = (size_t)M_ROWS * C_DIM;

    unsigned short* wt = wsb;                          // weights at [0, 8.85M shorts)
    float* qkvb    = ws + 4500000;                     // 2304 f32
    float* actb    = ws + 4505000;                     // 1536 f32
    float* act_res = ws + 1 * U;
    unsigned short* h_bf   = wsb + 4 * U;
    unsigned short* u_bf   = wsb + 5 * U;
    unsigned short* qkv_bf = wsb + 6 * U;              // [3U,4.5U) floats
    unsigned short* vt_bf  = wsb + 9 * U;              // [4.5U,5U)
    unsigned short* y_bf   = wsb + 4 * U;              // reuse h
    unsigned short* g_bf   = wsb + 5 * U;              // reuse u
    float*          x1     = ws  + 3 * U;              // reuse qkv head
    unsigned short* m_bf   = wsb + 8 * U;              // reuse qkv tail
    unsigned short* a1_bf  = wsb + 9 * U;              // reuse vt + beyond

    const size_t WCC = (size_t)C_DIM * C_DIM;
    unsigned short* Wt_actin = wt;                     // [1536][768] = Wt_act|Wt_in
    unsigned short* Wt_qkv   = wt + 2 * WCC;           // [2304][768] = Wtq|Wtk|Wtv
    unsigned short* Wtp      = wt + 5 * WCC;
    unsigned short* Wt_out   = wt + 6 * WCC;
    unsigned short* Wt1      = wt + 7 * WCC;                     // [3072][768]
    unsigned short* Wt2      = Wt1 + (size_t)C_DIM * 4 * C_DIM;  // [768][3072]

    const dim3 tb(32, 8);
    WPtrs wp;
    wp.p[0] = W_act; wp.p[1] = W_in; wp.p[2] = Wq; wp.p[3] = Wk;
    wp.p[4] = Wv;    wp.p[5] = Wp;   wp.p[6] = W_out;
    wtrans7_kernel<<<dim3(24, 24, 7), tb, 0, stream>>>(wp, wt);
    wtrans_kernel<<<dim3(4 * C_DIM / 32, C_DIM / 32), tb, 0, stream>>>(W1, Wt1, C_DIM, 4 * C_DIM);
    wtrans_kernel<<<dim3(C_DIM / 32, 4 * C_DIM / 32), tb, 0, stream>>>(W2, Wt2, 4 * C_DIM, C_DIM);
    biascat_kernel<<<9, 256, 0, stream>>>(bq, bk, bv, b_act, b_in, qkvb, actb);

    const dim3 blk(256);
    const dim3 g_actin(M_ROWS / GBM, 1536 / GBN);      // 48 x 12
    const dim3 g_qkv(M_ROWS / GBM, QKVC / GBN);        // 48 x 18
    const dim3 g_cc(M_ROWS / GBM, C_DIM / GBN);        // 48 x 6
    const dim3 g_c4(M_ROWS / GBM, 4 * C_DIM / GBN);    // 48 x 24
    const dim3 g_vt(T_SEQ / 32, HD / 32, B_SZ * NH);
    const dim3 g_attn(T_SEQ / 128, NH, B_SZ);

    // h = rmsnorm(x, g1)
    rmsnorm_kernel<<<M_ROWS, blk, 0, stream>>>(x, g1, h_bf);
    // [act_res | u] = silu(h @ [W_act|W_in] + [b_act|b_in])  (dual out)
    gemm_bf16<<<g_actin, blk, 0, stream>>>(h_bf, Wt_actin, actb, act_res, FNULL,
                                           (void*)u_bf, M_ROWS, 1536, C_DIM,
                                           ACT_SILU | OUT_BF16 | OUT_DUAL);
    // qkv = u @ [Wq|Wk|Wv] + [bq|bk|bv]  [bf16, M x 2304]
    gemm_bf16<<<g_qkv, blk, 0, stream>>>(u_bf, Wt_qkv, qkvb, FNULL, FNULL,
                                         (void*)qkv_bf, M_ROWS, QKVC, C_DIM, ACT_NONE | OUT_BF16);
    // vt = head-transpose(v)
    vtrans_kernel<<<g_vt, tb, 0, stream>>>(qkv_bf, vt_bf);
    // y = attention(qkv, vt)
    attn_mfma<<<g_attn, blk, 0, stream>>>(qkv_bf, vt_bf, y_bf);
    // g = (y @ Wp + bp) * act_res [bf16]
    gemm_bf16<<<g_cc, blk, 0, stream>>>(y_bf, Wtp, bp, act_res, FNULL,
                                        (void*)g_bf, M_ROWS, C_DIM, C_DIM, ACT_NONE | OUT_BF16);
    // x1 = x + g @ W_out + b_out [f32]
    gemm_bf16<<<g_cc, blk, 0, stream>>>(g_bf, Wt_out, b_out, FNULL, x,
                                        (void*)x1, M_ROWS, C_DIM, C_DIM, ACT_NONE);
    // m = rmsnorm(x1, g2) [bf16]
    rmsnorm_kernel<<<M_ROWS, blk, 0, stream>>>(x1, g2, m_bf);
    // a1 = gelu(m @ W1 + b1) [bf16]
    gemm_bf16<<<g_c4, blk, 0, stream>>>(m_bf, Wt1, b1, FNULL, FNULL,
                                        (void*)a1_bf, M_ROWS, 4 * C_DIM, C_DIM, ACT_GELU | OUT_BF16);
    // out = x1 + a1 @ W2 + b2 [f32]
    gemm_bf16<<<g_cc, blk, 0, stream>>>(a1_bf, Wt2, b2, FNULL, x1,
                                        (void*)out, M_ROWS, C_DIM, 4 * C_DIM, ACT_NONE);
}

// Round 8
// 699.870 us; speedup vs baseline: 10.4141x; 1.0416x over previous
//
#include <hip/hip_runtime.h>
#include <math.h>

// Problem constants (fixed by the reference)
#define B_SZ   4
#define T_SEQ  1536
#define C_DIM  768
#define QKVC   (3 * C_DIM)      // 2304
#define NH     12
#define HD     64
#define TBLK   512
#define M_ROWS (B_SZ * T_SEQ)   // 6144
#define NQT    12               // query tiles of 128
#define NFLAT  (B_SZ * NH * NQT)  // 576

// epilogue mode: low 3 bits = activation, bit 3 = bf16 out, bit 4 = dual-out
#define ACT_NONE 0
#define ACT_SILU 1
#define ACT_GELU 2
#define OUT_BF16 8
#define OUT_DUAL 16

typedef __attribute__((ext_vector_type(8))) short bf16x8;
typedef __attribute__((ext_vector_type(4))) float f32x4;

#define WAITCNT_VM(n) asm volatile("s_waitcnt vmcnt(" #n ")" ::: "memory")
#define WAITCNT_LGKM0 asm volatile("s_waitcnt lgkmcnt(0)" ::: "memory")

static __device__ __forceinline__ void gload_lds16(const void* g, void* l) {
    __builtin_amdgcn_global_load_lds(
        (const __attribute__((address_space(1))) void*)g,
        (__attribute__((address_space(3))) void*)l, 16, 0, 0);
}

// round-to-nearest-even f32 -> bf16 (bit pattern)
static __device__ __forceinline__ unsigned short f2bf(float f) {
    unsigned int u = __float_as_uint(f);
    u += 0x7fffu + ((u >> 16) & 1u);
    return (unsigned short)(u >> 16);
}

// ---------------------------------------------------------------------------
// Fused weight transpose for the 7 CxC weights
// ---------------------------------------------------------------------------
struct WPtrs { const float* p[7]; };

__global__ __launch_bounds__(256) void wtrans7_kernel(WPtrs w, unsigned short* out) {
    __shared__ float t[32][33];
    const int tx = threadIdx.x, ty = threadIdx.y;
    const int n0 = blockIdx.x * 32, k0 = blockIdx.y * 32;
    const float* in = w.p[blockIdx.z];
    unsigned short* o = out + (size_t)blockIdx.z * C_DIM * C_DIM;
    #pragma unroll
    for (int j = 0; j < 4; ++j)
        t[ty + 8 * j][tx] = in[(size_t)(k0 + ty + 8 * j) * C_DIM + n0 + tx];
    __syncthreads();
    #pragma unroll
    for (int j = 0; j < 4; ++j)
        o[(size_t)(n0 + ty + 8 * j) * C_DIM + k0 + tx] = f2bf(t[tx][ty + 8 * j]);
}

__global__ __launch_bounds__(256) void wtrans_kernel(const float* in, unsigned short* out, int K, int N) {
    __shared__ float t[32][33];
    const int tx = threadIdx.x, ty = threadIdx.y;
    const int n0 = blockIdx.x * 32, k0 = blockIdx.y * 32;
    #pragma unroll
    for (int j = 0; j < 4; ++j)
        t[ty + 8 * j][tx] = in[(size_t)(k0 + ty + 8 * j) * N + n0 + tx];
    __syncthreads();
    #pragma unroll
    for (int j = 0; j < 4; ++j)
        out[(size_t)(n0 + ty + 8 * j) * K + k0 + tx] = f2bf(t[tx][ty + 8 * j]);
}

__global__ __launch_bounds__(256) void biascat_kernel(const float* bq, const float* bk, const float* bv,
                                                      const float* ba, const float* bi,
                                                      float* qkvb, float* actb) {
    const int i = blockIdx.x * 256 + threadIdx.x;
    if (i < 2304) qkvb[i] = (i < 768) ? bq[i] : ((i < 1536) ? bk[i - 768] : bv[i - 1536]);
    if (i < 1536) actb[i] = (i < 768) ? ba[i] : bi[i - 768];
}

// ---------------------------------------------------------------------------
// bf16 head-transpose of V (from fused qkv): qkv [B*T][2304] -> vt [B*H*64][T]
// ---------------------------------------------------------------------------
__global__ __launch_bounds__(256) void vtrans_kernel(const unsigned short* in, unsigned short* out) {
    __shared__ unsigned short t[32][33];
    const int tx = threadIdx.x, ty = threadIdx.y;
    const int t0 = blockIdx.x * 32;
    const int d0 = blockIdx.y * 32;
    const int z  = blockIdx.z;
    const int b  = z / NH, h = z % NH;
    #pragma unroll
    for (int j = 0; j < 4; ++j)
        t[ty + 8 * j][tx] = in[((size_t)b * T_SEQ + t0 + ty + 8 * j) * QKVC + 2 * C_DIM + h * HD + d0 + tx];
    __syncthreads();
    #pragma unroll
    for (int j = 0; j < 4; ++j)
        out[((size_t)z * HD + d0 + ty + 8 * j) * T_SEQ + t0 + tx] = t[tx][ty + 8 * j];
}

// ---------------------------------------------------------------------------
// RMSNorm -> bf16 output
// ---------------------------------------------------------------------------
__global__ __launch_bounds__(256) void rmsnorm_kernel(const float* x, const float* g, unsigned short* out) {
    const int row = blockIdx.x;
    const int tid = threadIdx.x;
    const float* xr = x + (size_t)row * C_DIM;

    const float v0 = xr[tid];
    const float v1 = xr[tid + 256];
    const float v2 = xr[tid + 512];
    float ss = v0 * v0 + v1 * v1 + v2 * v2;

    #pragma unroll
    for (int off = 32; off > 0; off >>= 1) ss += __shfl_xor(ss, off, 64);
    __shared__ float s_red[4];
    if ((tid & 63) == 0) s_red[tid >> 6] = ss;
    __syncthreads();
    ss = s_red[0] + s_red[1] + s_red[2] + s_red[3];

    const float r = rsqrtf(ss * (1.0f / C_DIM) + 1e-6f);
    unsigned short* orow = out + (size_t)row * C_DIM;
    orow[tid]       = f2bf(v0 * r * g[tid]);
    orow[tid + 256] = f2bf(v1 * r * g[tid + 256]);
    orow[tid + 512] = f2bf(v2 * r * g[tid + 512]);
}

// ---------------------------------------------------------------------------
// bf16 MFMA GEMM (templated tile): out = [resid +] ( act(A @ Bt^T + bias) [* gmul] )
// TBM x TBN tile, BK=64, 4 waves; double-buffered gload_lds + counted vmcnt;
// XOR-swizzled source/read (2-way conflicts).
//   128x128: waves 2x2, 8 loads/thread/stage, LDS 64KB
//    64x128: waves 1x4, 6 loads/thread/stage, LDS 48KB (for N=768 GEMMs)
// ---------------------------------------------------------------------------
template<int TBM, int TBN>
__global__ __launch_bounds__(256) void gemm_t(const unsigned short* A, const unsigned short* Bt,
                                              const float* bias, const float* gmul, const float* resid,
                                              void* outp, int M, int N, int K, int mode) {
    constexpr int WN  = (TBM == 128) ? 2 : 4;    // waves along N
    constexpr int WNC = TBN / WN;                // cols per wave (64 or 32)
    constexpr int FM  = 4;                       // 64 rows per wave always
    constexpr int FN  = WNC / 16;                // 4 or 2
    constexpr int NA  = TBM / 8;                 // A 1KB-chunks
    constexpr int NB  = TBN / 8;
    constexpr int LA  = NA / 4, LB = NB / 4;
    constexpr int LPT = LA + LB;                 // loads per thread per stage

    __shared__ unsigned short As[2][TBM * 64];
    __shared__ unsigned short Bs[2][TBN * 64];

    const int tid  = threadIdx.x;
    const int lane = tid & 63;
    const int wid  = tid >> 6;
    const int wr   = wid / WN;
    const int wc   = wid % WN;
    const int m0   = blockIdx.x * TBM;
    const int n0   = blockIdx.y * TBN;

    const int l15 = lane & 15;
    const int l4  = lane >> 4;

    const int lrow = lane >> 3;
    const int csw  = (((lane & 7) ^ lrow) << 4);   // swizzled source byte col

    f32x4 acc[FM][FN] = {};

    const char* Ab = (const char*)A;
    const char* Bb = (const char*)Bt;

    auto stage = [&](int buf, int k0) {
        char* Ad = (char*)&As[buf][0];
        char* Bd = (char*)&Bs[buf][0];
        #pragma unroll
        for (int j = 0; j < LA; ++j) {
            const int chunk = wid * LA + j;
            const int row   = chunk * 8 + lrow;
            gload_lds16(Ab + ((size_t)(m0 + row) * K + k0) * 2 + csw, Ad + chunk * 1024);
        }
        #pragma unroll
        for (int j = 0; j < LB; ++j) {
            const int chunk = wid * LB + j;
            const int row   = chunk * 8 + lrow;
            gload_lds16(Bb + ((size_t)(n0 + row) * K + k0) * 2 + csw, Bd + chunk * 1024);
        }
    };

    stage(0, 0);
    int cur = 0;
    for (int k0 = 0; k0 < K; k0 += 64) {
        if (k0 + 64 < K) {
            stage(cur ^ 1, k0 + 64);
            if constexpr (LPT == 8) { WAITCNT_VM(8); } else { WAITCNT_VM(6); }
        } else {
            WAITCNT_VM(0);
        }
        __builtin_amdgcn_s_barrier();
        __builtin_amdgcn_sched_barrier(0);

        const unsigned short* Ac = &As[cur][0];
        const unsigned short* Bc = &Bs[cur][0];
        #pragma unroll
        for (int kk = 0; kk < 2; ++kk) {
            bf16x8 af[FM], bfr[FN];
            const int g = l4 + 4 * kk;
            #pragma unroll
            for (int fm = 0; fm < FM; ++fm)
                af[fm] = *(const bf16x8*)&Ac[(wr * 64 + fm * 16 + l15) * 64 + ((g ^ (l15 & 7)) * 8)];
            #pragma unroll
            for (int fn = 0; fn < FN; ++fn)
                bfr[fn] = *(const bf16x8*)&Bc[(wc * WNC + fn * 16 + l15) * 64 + ((g ^ (l15 & 7)) * 8)];
            #pragma unroll
            for (int fm = 0; fm < FM; ++fm)
                #pragma unroll
                for (int fn = 0; fn < FN; ++fn)
                    acc[fm][fn] = __builtin_amdgcn_mfma_f32_16x16x32_bf16(
                        af[fm], bfr[fn], acc[fm][fn], 0, 0, 0);
        }

        WAITCNT_LGKM0;
        __builtin_amdgcn_s_barrier();
        cur ^= 1;
    }

    const int act = mode & 7;
    #pragma unroll
    for (int fm = 0; fm < FM; ++fm) {
        #pragma unroll
        for (int r = 0; r < 4; ++r) {
            const int m = m0 + wr * 64 + fm * 16 + l4 * 4 + r;
            #pragma unroll
            for (int fn = 0; fn < FN; ++fn) {
                const int n = n0 + wc * WNC + fn * 16 + l15;
                float v = acc[fm][fn][r];
                if (bias) v += bias[n];
                if (act == ACT_SILU) {
                    v = v / (1.0f + expf(-v));
                } else if (act == ACT_GELU) {
                    v = 0.5f * v * (1.0f + erff(v * 0.70710678118654752f));
                }
                if (mode & OUT_DUAL) {
                    if (n < 768) ((float*)gmul)[(size_t)m * 768 + n] = v;
                    else ((unsigned short*)outp)[(size_t)m * 768 + (n - 768)] = f2bf(v);
                } else {
                    if (gmul)  v *= gmul[(size_t)m * N + n];
                    if (resid) v += resid[(size_t)m * N + n];
                    if (mode & OUT_BF16) ((unsigned short*)outp)[(size_t)m * N + n] = f2bf(v);
                    else                 ((float*)outp)[(size_t)m * N + n] = v;
                }
            }
        }
    }
}

// ---------------------------------------------------------------------------
// MFMA block-causal flash attention, SPLIT over key-blocks (kb), with
// double-buffered K/V staging (counted vmcnt, raw barriers).
// grid (qt=12, h=12, b*3+kb); each block: K-tiles jt=0..2qb+1 of its kb.
// Writes partial O (f32), m, l; merge kernel combines the 3 kb partials.
// LDS: Qs 16K + Ks 2x8K + Vs 2x8K + Pl 18K = 66.4 KB -> 2 blocks/CU.
// ---------------------------------------------------------------------------
#define PPITCH 72

__global__ __launch_bounds__(256) void attn_mfma(const unsigned short* qkv, const unsigned short* vt,
                                                 float* Opart, float* mpart, float* lpart) {
    __shared__ unsigned short Qs[128 * 64];
    __shared__ unsigned short Ks[2][64 * 64];
    __shared__ unsigned short Vs[2][64 * 64];
    __shared__ unsigned short Pl[128 * PPITCH];

    const int tid  = threadIdx.x;
    const int lane = tid & 63;
    const int w    = tid >> 6;
    const int l15  = lane & 15;
    const int l4   = lane >> 4;
    const int qt   = blockIdx.x;
    const int h    = blockIdx.y;
    const int b    = blockIdx.z / 3;
    const int kb   = blockIdx.z % 3;
    const int i0   = qt * 128;
    const int qb   = qt & 3;

    const size_t bT = (size_t)b * T_SEQ;
    const unsigned short* qp = qkv + bT * QKVC + h * HD;
    const unsigned short* kp = qkv + bT * QKVC + C_DIM + h * HD;
    const size_t vtb = (size_t)(b * NH + h) * HD * T_SEQ;
    const int flat = (b * NH + h) * NQT + qt;

    const int lr   = lane >> 3;
    const int csrc = ((lane & 7) ^ lr) * 8;

    // stage Q (128 x 64)
    #pragma unroll
    for (int i = 0; i < 4; ++i) {
        const int row = w * 32 + i * 8 + lr;
        gload_lds16(qp + (size_t)(i0 + row) * QKVC + csrc,
                    (char*)Qs + (w * 32 + i * 8) * 128);
    }

    auto stage_kv = [&](int buf, int jt) {
        const int j0 = kb * TBLK + jt * 64;
        #pragma unroll
        for (int i = 0; i < 2; ++i) {
            const int row = w * 8 + i * 32 + lr;
            gload_lds16(kp + (size_t)(j0 + row) * QKVC + csrc,
                        (char*)&Ks[buf][0] + (w * 8 + i * 32) * 128);
            gload_lds16(vt + vtb + (size_t)row * T_SEQ + j0 + csrc,
                        (char*)&Vs[buf][0] + (w * 8 + i * 32) * 128);
        }
    };

    f32x4 o[2][4] = {};
    float m_run[2][4], l_run[2][4];
    #pragma unroll
    for (int a = 0; a < 2; ++a)
        #pragma unroll
        for (int r = 0; r < 4; ++r) { m_run[a][r] = -INFINITY; l_run[a][r] = 0.f; }

    const int jt_max = 2 * qb + 1;
    stage_kv(0, 0);
    int cur = 0;
    for (int jt = 0; jt <= jt_max; ++jt) {
        const bool diag = (jt >= 2 * qb);

        if (jt < jt_max) {
            stage_kv(cur ^ 1, jt + 1);
            WAITCNT_VM(4);        // current tile (+Q on first iter) landed
        } else {
            WAITCNT_VM(0);
        }
        __builtin_amdgcn_s_barrier();
        __builtin_amdgcn_sched_barrier(0);

        // ---- S = Q K^T ----
        f32x4 s[2][4] = {};
        #pragma unroll
        for (int kk = 0; kk < 2; ++kk) {
            bf16x8 af[2], bfr[4];
            #pragma unroll
            for (int a = 0; a < 2; ++a)
                af[a] = *(const bf16x8*)&Qs[(w * 32 + a * 16 + l15) * 64 + (((l4 + 4 * kk) ^ (l15 & 7)) * 8)];
            #pragma unroll
            for (int n = 0; n < 4; ++n)
                bfr[n] = *(const bf16x8*)&Ks[cur][(n * 16 + l15) * 64 + (((l4 + 4 * kk) ^ (l15 & 7)) * 8)];
            #pragma unroll
            for (int a = 0; a < 2; ++a)
                #pragma unroll
                for (int n = 0; n < 4; ++n)
                    s[a][n] = __builtin_amdgcn_mfma_f32_16x16x32_bf16(af[a], bfr[n], s[a][n], 0, 0, 0);
        }

        // ---- scale + mask + online softmax + P write ----
        #pragma unroll
        for (int a = 0; a < 2; ++a) {
            #pragma unroll
            for (int r = 0; r < 4; ++r) {
                const int imod = qb * 128 + w * 32 + a * 16 + l4 * 4 + r;
                float pv[4];
                float rowm = -INFINITY;
                #pragma unroll
                for (int n = 0; n < 4; ++n) {
                    float sv = s[a][n][r] * 0.125f;
                    if (diag) {
                        const int jmod = jt * 64 + n * 16 + l15;
                        if (jmod > imod) sv = -INFINITY;
                    }
                    pv[n] = sv;
                    rowm = fmaxf(rowm, sv);
                }
                #pragma unroll
                for (int off = 1; off < 16; off <<= 1) rowm = fmaxf(rowm, __shfl_xor(rowm, off, 64));
                const float mn = fmaxf(m_run[a][r], rowm);
                const float sc = __expf(m_run[a][r] - mn);
                float rs = 0.f;
                #pragma unroll
                for (int n = 0; n < 4; ++n) {
                    const float e = __expf(pv[n] - mn);
                    pv[n] = e;
                    rs += e;
                }
                #pragma unroll
                for (int off = 1; off < 16; off <<= 1) rs += __shfl_xor(rs, off, 64);
                l_run[a][r] = l_run[a][r] * sc + rs;
                m_run[a][r] = mn;
                const int qrow = w * 32 + a * 16 + l4 * 4 + r;
                #pragma unroll
                for (int n = 0; n < 4; ++n) {
                    o[a][n][r] *= sc;
                    Pl[qrow * PPITCH + n * 16 + l15] = f2bf(pv[n]);
                }
            }
        }
        WAITCNT_LGKM0;                       // P writes visible (keep vmcnt in flight)
        __builtin_amdgcn_s_barrier();
        __builtin_amdgcn_sched_barrier(0);

        // ---- O += P V ----
        #pragma unroll
        for (int kk = 0; kk < 2; ++kk) {
            bf16x8 af[2], bfr[4];
            #pragma unroll
            for (int a = 0; a < 2; ++a)
                af[a] = *(const bf16x8*)&Pl[(w * 32 + a * 16 + l15) * PPITCH + l4 * 8 + kk * 32];
            #pragma unroll
            for (int n = 0; n < 4; ++n)
                bfr[n] = *(const bf16x8*)&Vs[cur][(n * 16 + l15) * 64 + (((l4 + 4 * kk) ^ (l15 & 7)) * 8)];
            #pragma unroll
            for (int a = 0; a < 2; ++a)
                #pragma unroll
                for (int n = 0; n < 4; ++n)
                    o[a][n] = __builtin_amdgcn_mfma_f32_16x16x32_bf16(af[a], bfr[n], o[a][n], 0, 0, 0);
        }

        WAITCNT_LGKM0;                       // PV ds_reads done before buffer reuse
        __builtin_amdgcn_s_barrier();
        __builtin_amdgcn_sched_barrier(0);
        cur ^= 1;
    }

    // ---- write partials ----
    float* Ob = Opart + ((size_t)kb * NFLAT + flat) * (128 * 64);
    #pragma unroll
    for (int a = 0; a < 2; ++a) {
        #pragma unroll
        for (int r = 0; r < 4; ++r) {
            const int qq = w * 32 + a * 16 + l4 * 4 + r;
            #pragma unroll
            for (int n = 0; n < 4; ++n)
                Ob[(size_t)qq * 64 + n * 16 + l15] = o[a][n][r];
            if (l15 == 0) {
                mpart[((size_t)kb * NFLAT + flat) * 128 + qq] = m_run[a][r];
                lpart[((size_t)kb * NFLAT + flat) * 128 + qq] = l_run[a][r];
            }
        }
    }
}

// ---------------------------------------------------------------------------
// Merge the 3 kb partials: y = (sum_i O_i e^{m_i-m*}) / (sum_i l_i e^{m_i-m*})
// grid = NFLAT blocks; thread t: row = t>>1, cols [(t&1)*32, +32)
// ---------------------------------------------------------------------------
__global__ __launch_bounds__(256) void attn_merge(const float* Opart, const float* mpart, const float* lpart,
                                                  unsigned short* y) {
    const int flat = blockIdx.x;
    const int qt = flat % NQT;
    const int h  = (flat / NQT) % NH;
    const int b  = flat / (NQT * NH);
    const int t  = threadIdx.x;
    const int r  = t >> 1;
    const int c0 = (t & 1) * 32;

    const size_t rowoff = (size_t)flat * 128 + r;
    float m0 = mpart[0 * (size_t)NFLAT * 128 + rowoff];
    float m1 = mpart[1 * (size_t)NFLAT * 128 + rowoff];
    float m2 = mpart[2 * (size_t)NFLAT * 128 + rowoff];
    const float ms = fmaxf(fmaxf(m0, m1), m2);
    const float w0 = __expf(m0 - ms), w1 = __expf(m1 - ms), w2 = __expf(m2 - ms);
    const float ls = lpart[0 * (size_t)NFLAT * 128 + rowoff] * w0 +
                     lpart[1 * (size_t)NFLAT * 128 + rowoff] * w1 +
                     lpart[2 * (size_t)NFLAT * 128 + rowoff] * w2;
    const float inv = 1.0f / ls;

    const size_t obase = ((size_t)flat * 128 + r) * 64 + c0;
    const float* O0 = Opart + 0 * (size_t)NFLAT * 128 * 64 + obase;
    const float* O1 = Opart + 1 * (size_t)NFLAT * 128 * 64 + obase;
    const float* O2 = Opart + 2 * (size_t)NFLAT * 128 * 64 + obase;

    unsigned short* yp = y + ((size_t)b * T_SEQ + qt * 128 + r) * C_DIM + h * HD + c0;
    #pragma unroll
    for (int j = 0; j < 8; ++j) {
        const float4 a = *reinterpret_cast<const float4*>(O0 + j * 4);
        const float4 bq = *reinterpret_cast<const float4*>(O1 + j * 4);
        const float4 cq = *reinterpret_cast<const float4*>(O2 + j * 4);
        ushort4 ov;
        ov.x = f2bf((a.x * w0 + bq.x * w1 + cq.x * w2) * inv);
        ov.y = f2bf((a.y * w0 + bq.y * w1 + cq.y * w2) * inv);
        ov.z = f2bf((a.z * w0 + bq.z * w1 + cq.z * w2) * inv);
        ov.w = f2bf((a.w * w0 + bq.w * w1 + cq.w * w2) * inv);
        *reinterpret_cast<ushort4*>(yp + j * 4) = ov;
    }
}

// ---------------------------------------------------------------------------
// Launcher. Workspace (float units U = 4,718,592; ~8.1U = 153 MB):
//  [0,0.94U) weights bf16; qkvb/actb f32 @4.50M/4.505M
//  [1U,2U) act_res | [2U,2.5U) h/y | [2.5U,3U) u/g | [3U,4.5U) qkv
//  [4.5U,5U) vt | x1 @[3U,4U) after attn | m_bf @[4U,4.5U) after attn
//  [5U,8U) Opart | [8U,8.1U) mpart/lpart | a1 @[4.5U,6.5U) after merge
// ---------------------------------------------------------------------------
extern "C" void kernel_launch(void* const* d_in, const int* in_sizes, int n_in,
                              void* d_out, int out_size, void* d_ws, size_t ws_size,
                              hipStream_t stream) {
    const float* x     = (const float*)d_in[0];
    const float* g1    = (const float*)d_in[1];
    const float* g2    = (const float*)d_in[2];
    const float* W_in  = (const float*)d_in[3];
    const float* b_in  = (const float*)d_in[4];
    const float* W_act = (const float*)d_in[5];
    const float* b_act = (const float*)d_in[6];
    const float* W_out = (const float*)d_in[7];
    const float* b_out = (const float*)d_in[8];
    const float* Wq    = (const float*)d_in[9];
    const float* bq    = (const float*)d_in[10];
    const float* Wk    = (const float*)d_in[11];
    const float* bk    = (const float*)d_in[12];
    const float* Wv    = (const float*)d_in[13];
    const float* bv    = (const float*)d_in[14];
    const float* Wp    = (const float*)d_in[15];
    const float* bp    = (const float*)d_in[16];
    const float* W1    = (const float*)d_in[17];
    const float* b1    = (const float*)d_in[18];
    const float* W2    = (const float*)d_in[19];
    const float* b2    = (const float*)d_in[20];
    float* out = (float*)d_out;

    const float* FNULL = 0;

    float* ws = (float*)d_ws;
    unsigned short* wsb = (unsigned short*)d_ws;
    const size_t U = (size_t)M_ROWS * C_DIM;

    unsigned short* wt = wsb;
    float* qkvb    = ws + 4500000;
    float* actb    = ws + 4505000;
    float* act_res = ws + 1 * U;
    unsigned short* h_bf   = wsb + 4 * U;
    unsigned short* u_bf   = wsb + 5 * U;
    unsigned short* qkv_bf = wsb + 6 * U;
    unsigned short* vt_bf  = wsb + 9 * U;
    unsigned short* y_bf   = wsb + 4 * U;
    unsigned short* g_bf   = wsb + 5 * U;
    float*          x1     = ws  + 3 * U;
    unsigned short* m_bf   = wsb + 8 * U;
    unsigned short* a1_bf  = wsb + 9 * U;
    float* Opart = ws + 5 * U;                 // 3*576*8192 = 3U exactly
    float* mpart = ws + 8 * U;
    float* lpart = ws + 8 * U + (size_t)3 * NFLAT * 128;

    const size_t WCC = (size_t)C_DIM * C_DIM;
    unsigned short* Wt_actin = wt;
    unsigned short* Wt_qkv   = wt + 2 * WCC;
    unsigned short* Wtp      = wt + 5 * WCC;
    unsigned short* Wt_out   = wt + 6 * WCC;
    unsigned short* Wt1      = wt + 7 * WCC;
    unsigned short* Wt2      = Wt1 + (size_t)C_DIM * 4 * C_DIM;

    const dim3 tb(32, 8);
    WPtrs wp;
    wp.p[0] = W_act; wp.p[1] = W_in; wp.p[2] = Wq; wp.p[3] = Wk;
    wp.p[4] = Wv;    wp.p[5] = Wp;   wp.p[6] = W_out;
    wtrans7_kernel<<<dim3(24, 24, 7), tb, 0, stream>>>(wp, wt);
    wtrans_kernel<<<dim3(4 * C_DIM / 32, C_DIM / 32), tb, 0, stream>>>(W1, Wt1, C_DIM, 4 * C_DIM);
    wtrans_kernel<<<dim3(C_DIM / 32, 4 * C_DIM / 32), tb, 0, stream>>>(W2, Wt2, 4 * C_DIM, C_DIM);
    biascat_kernel<<<9, 256, 0, stream>>>(bq, bk, bv, b_act, b_in, qkvb, actb);

    const dim3 blk(256);
    const dim3 g_actin(M_ROWS / 128, 1536 / 128);
    const dim3 g_qkv(M_ROWS / 128, QKVC / 128);
    const dim3 g_cc64(M_ROWS / 64, C_DIM / 128);       // 96 x 6 = 576
    const dim3 g_c4(M_ROWS / 128, 4 * C_DIM / 128);
    const dim3 g_vt(T_SEQ / 32, HD / 32, B_SZ * NH);
    const dim3 g_attn(NQT, NH, B_SZ * 3);

    // h = rmsnorm(x, g1)
    rmsnorm_kernel<<<M_ROWS, blk, 0, stream>>>(x, g1, h_bf);
    // [act_res | u] = silu(h @ [W_act|W_in] + [b_act|b_in])
    gemm_t<128,128><<<g_actin, blk, 0, stream>>>(h_bf, Wt_actin, actb, act_res, FNULL,
                                                 (void*)u_bf, M_ROWS, 1536, C_DIM,
                                                 ACT_SILU | OUT_BF16 | OUT_DUAL);
    // qkv = u @ [Wq|Wk|Wv] + b
    gemm_t<128,128><<<g_qkv, blk, 0, stream>>>(u_bf, Wt_qkv, qkvb, FNULL, FNULL,
                                               (void*)qkv_bf, M_ROWS, QKVC, C_DIM, ACT_NONE | OUT_BF16);
    // vt = head-transpose(v)
    vtrans_kernel<<<g_vt, tb, 0, stream>>>(qkv_bf, vt_bf);
    // attention partials + merge
    attn_mfma<<<g_attn, blk, 0, stream>>>(qkv_bf, vt_bf, Opart, mpart, lpart);
    attn_merge<<<NFLAT, blk, 0, stream>>>(Opart, mpart, lpart, y_bf);
    // g = (y @ Wp + bp) * act_res
    gemm_t<64,128><<<g_cc64, blk, 0, stream>>>(y_bf, Wtp, bp, act_res, FNULL,
                                               (void*)g_bf, M_ROWS, C_DIM, C_DIM, ACT_NONE | OUT_BF16);
    // x1 = x + g @ W_out + b_out
    gemm_t<64,128><<<g_cc64, blk, 0, stream>>>(g_bf, Wt_out, b_out, FNULL, x,
                                               (void*)x1, M_ROWS, C_DIM, C_DIM, ACT_NONE);
    // m = rmsnorm(x1, g2)
    rmsnorm_kernel<<<M_ROWS, blk, 0, stream>>>(x1, g2, m_bf);
    // a1 = gelu(m @ W1 + b1)
    gemm_t<128,128><<<g_c4, blk, 0, stream>>>(m_bf, Wt1, b1, FNULL, FNULL,
                                              (void*)a1_bf, M_ROWS, 4 * C_DIM, C_DIM, ACT_GELU | OUT_BF16);
    // out = x1 + a1 @ W2 + b2
    gemm_t<64,128><<<g_cc64, blk, 0, stream>>>(a1_bf, Wt2, b2, FNULL, x1,
                                               (void*)out, M_ROWS, C_DIM, 4 * C_DIM, ACT_NONE);
}

// Round 9
// 601.938 us; speedup vs baseline: 12.1084x; 1.1627x over previous
//
#include <hip/hip_runtime.h>
#include <math.h>

// Problem constants (fixed by the reference)
#define B_SZ   4
#define T_SEQ  1536
#define C_DIM  768
#define QKVC   (3 * C_DIM)      // 2304
#define NH     12
#define HD     64
#define TBLK   512
#define M_ROWS (B_SZ * T_SEQ)   // 6144
#define NQT    12               // query tiles of 128
#define NFLAT  (B_SZ * NH * NQT)  // 576

// epilogue mode: low 3 bits = activation, bit 3 = bf16 out, bit 4 = dual-out
#define ACT_NONE 0
#define ACT_SILU 1
#define ACT_GELU 2
#define OUT_BF16 8
#define OUT_DUAL 16

typedef __attribute__((ext_vector_type(8))) short bf16x8;
typedef __attribute__((ext_vector_type(4))) float f32x4;

#define WAITCNT_VM(n) asm volatile("s_waitcnt vmcnt(" #n ")" ::: "memory")
#define WAITCNT_LGKM0 asm volatile("s_waitcnt lgkmcnt(0)" ::: "memory")

static __device__ __forceinline__ void gload_lds16(const void* g, void* l) {
    __builtin_amdgcn_global_load_lds(
        (const __attribute__((address_space(1))) void*)g,
        (__attribute__((address_space(3))) void*)l, 16, 0, 0);
}

// round-to-nearest-even f32 -> bf16 (bit pattern)
static __device__ __forceinline__ unsigned short f2bf(float f) {
    unsigned int u = __float_as_uint(f);
    u += 0x7fffu + ((u >> 16) & 1u);
    return (unsigned short)(u >> 16);
}

// SiLU via fast exp + hw rcp (rel err ~3e-7, invisible at bf16/tolerance)
static __device__ __forceinline__ float silu_f(float x) {
    return x * __builtin_amdgcn_rcpf(1.0f + __expf(-x));
}

// Exact GELU via Abramowitz-Stegun 7.1.26 erf poly (max abs err 1.5e-7)
static __device__ __forceinline__ float gelu_f(float x) {
    const float ax = fabsf(x) * 0.70710678118654752f;
    const float t  = __builtin_amdgcn_rcpf(1.0f + 0.3275911f * ax);
    const float e  = __expf(-ax * ax);
    float p = ((((1.061405429f * t - 1.453152027f) * t) + 1.421413741f) * t
               - 0.284496736f) * t + 0.254829592f;
    float erfv = 1.0f - p * t * e;
    erfv = (x < 0.f) ? -erfv : erfv;
    return 0.5f * x * (1.0f + erfv);
}

// ---------------------------------------------------------------------------
// Fused weight transpose for the 7 CxC weights
// ---------------------------------------------------------------------------
struct WPtrs { const float* p[7]; };

__global__ __launch_bounds__(256) void wtrans7_kernel(WPtrs w, unsigned short* out) {
    __shared__ float t[32][33];
    const int tx = threadIdx.x, ty = threadIdx.y;
    const int n0 = blockIdx.x * 32, k0 = blockIdx.y * 32;
    const float* in = w.p[blockIdx.z];
    unsigned short* o = out + (size_t)blockIdx.z * C_DIM * C_DIM;
    #pragma unroll
    for (int j = 0; j < 4; ++j)
        t[ty + 8 * j][tx] = in[(size_t)(k0 + ty + 8 * j) * C_DIM + n0 + tx];
    __syncthreads();
    #pragma unroll
    for (int j = 0; j < 4; ++j)
        o[(size_t)(n0 + ty + 8 * j) * C_DIM + k0 + tx] = f2bf(t[tx][ty + 8 * j]);
}

__global__ __launch_bounds__(256) void wtrans_kernel(const float* in, unsigned short* out, int K, int N) {
    __shared__ float t[32][33];
    const int tx = threadIdx.x, ty = threadIdx.y;
    const int n0 = blockIdx.x * 32, k0 = blockIdx.y * 32;
    #pragma unroll
    for (int j = 0; j < 4; ++j)
        t[ty + 8 * j][tx] = in[(size_t)(k0 + ty + 8 * j) * N + n0 + tx];
    __syncthreads();
    #pragma unroll
    for (int j = 0; j < 4; ++j)
        out[(size_t)(n0 + ty + 8 * j) * K + k0 + tx] = f2bf(t[tx][ty + 8 * j]);
}

__global__ __launch_bounds__(256) void biascat_kernel(const float* bq, const float* bk, const float* bv,
                                                      const float* ba, const float* bi,
                                                      float* qkvb, float* actb) {
    const int i = blockIdx.x * 256 + threadIdx.x;
    if (i < 2304) qkvb[i] = (i < 768) ? bq[i] : ((i < 1536) ? bk[i - 768] : bv[i - 1536]);
    if (i < 1536) actb[i] = (i < 768) ? ba[i] : bi[i - 768];
}

// ---------------------------------------------------------------------------
// bf16 head-transpose of V (from fused qkv): qkv [B*T][2304] -> vt [B*H*64][T]
// ---------------------------------------------------------------------------
__global__ __launch_bounds__(256) void vtrans_kernel(const unsigned short* in, unsigned short* out) {
    __shared__ unsigned short t[32][33];
    const int tx = threadIdx.x, ty = threadIdx.y;
    const int t0 = blockIdx.x * 32;
    const int d0 = blockIdx.y * 32;
    const int z  = blockIdx.z;
    const int b  = z / NH, h = z % NH;
    #pragma unroll
    for (int j = 0; j < 4; ++j)
        t[ty + 8 * j][tx] = in[((size_t)b * T_SEQ + t0 + ty + 8 * j) * QKVC + 2 * C_DIM + h * HD + d0 + tx];
    __syncthreads();
    #pragma unroll
    for (int j = 0; j < 4; ++j)
        out[((size_t)z * HD + d0 + ty + 8 * j) * T_SEQ + t0 + tx] = t[tx][ty + 8 * j];
}

// ---------------------------------------------------------------------------
// RMSNorm -> bf16 output
// ---------------------------------------------------------------------------
__global__ __launch_bounds__(256) void rmsnorm_kernel(const float* x, const float* g, unsigned short* out) {
    const int row = blockIdx.x;
    const int tid = threadIdx.x;
    const float* xr = x + (size_t)row * C_DIM;

    const float v0 = xr[tid];
    const float v1 = xr[tid + 256];
    const float v2 = xr[tid + 512];
    float ss = v0 * v0 + v1 * v1 + v2 * v2;

    #pragma unroll
    for (int off = 32; off > 0; off >>= 1) ss += __shfl_xor(ss, off, 64);
    __shared__ float s_red[4];
    if ((tid & 63) == 0) s_red[tid >> 6] = ss;
    __syncthreads();
    ss = s_red[0] + s_red[1] + s_red[2] + s_red[3];

    const float r = rsqrtf(ss * (1.0f / C_DIM) + 1e-6f);
    unsigned short* orow = out + (size_t)row * C_DIM;
    orow[tid]       = f2bf(v0 * r * g[tid]);
    orow[tid + 256] = f2bf(v1 * r * g[tid + 256]);
    orow[tid + 512] = f2bf(v2 * r * g[tid + 512]);
}

// ---------------------------------------------------------------------------
// bf16 MFMA GEMM, m97 structure: SINGLE-buffer LDS, 2-barrier K-loop,
// cross-block wave overlap hides the staging drain (4 blocks/CU).
// XOR-swizzled source + reads (2-way conflict floor).
//   TBM=128: waves 2x2 (64x64 each), LDS 32 KB
//   TBM=64 : waves 1x4 (64x32 each), LDS 24.5 KB   (N=768 GEMMs)
// ---------------------------------------------------------------------------
template<int TBM>
__global__ __launch_bounds__(256, 4) void gemm_t(const unsigned short* A, const unsigned short* Bt,
                                                 const float* bias, const float* gmul, const float* resid,
                                                 void* outp, int M, int N, int K, int mode) {
    constexpr int TBN = 128;
    constexpr int WN  = (TBM == 128) ? 2 : 4;    // waves along N
    constexpr int WNC = TBN / WN;                // cols per wave (64 or 32)
    constexpr int FM  = 4;                       // 64 rows per wave
    constexpr int FN  = WNC / 16;                // 4 or 2
    constexpr int LA  = TBM / 32;                // A chunks per wave (4 or 2)
    constexpr int LB  = 4;                       // B chunks per wave

    __shared__ unsigned short As[TBM * 64];
    __shared__ unsigned short Bs[TBN * 64];

    const int tid  = threadIdx.x;
    const int lane = tid & 63;
    const int wid  = tid >> 6;
    const int wr   = wid / WN;
    const int wc   = wid % WN;
    const int m0   = blockIdx.x * TBM;
    const int n0   = blockIdx.y * TBN;

    const int l15 = lane & 15;
    const int l4  = lane >> 4;

    const int lrow = lane >> 3;
    const int csw  = (((lane & 7) ^ lrow) << 4);   // swizzled source byte col

    f32x4 acc[FM][FN] = {};

    const char* Ab = (const char*)A;
    const char* Bb = (const char*)Bt;

    for (int k0 = 0; k0 < K; k0 += 64) {
        __syncthreads();   // previous compute done with LDS
        #pragma unroll
        for (int j = 0; j < LA; ++j) {
            const int chunk = wid * LA + j;
            const int row   = chunk * 8 + lrow;
            gload_lds16(Ab + ((size_t)(m0 + row) * K + k0) * 2 + csw, (char*)As + chunk * 1024);
        }
        #pragma unroll
        for (int j = 0; j < LB; ++j) {
            const int chunk = wid * LB + j;
            const int row   = chunk * 8 + lrow;
            gload_lds16(Bb + ((size_t)(n0 + row) * K + k0) * 2 + csw, (char*)Bs + chunk * 1024);
        }
        __syncthreads();   // drains vmcnt -> tiles ready

        #pragma unroll
        for (int kk = 0; kk < 2; ++kk) {
            bf16x8 af[FM], bfr[FN];
            const int g = l4 + 4 * kk;
            #pragma unroll
            for (int fm = 0; fm < FM; ++fm)
                af[fm] = *(const bf16x8*)&As[(wr * 64 + fm * 16 + l15) * 64 + ((g ^ (l15 & 7)) * 8)];
            #pragma unroll
            for (int fn = 0; fn < FN; ++fn)
                bfr[fn] = *(const bf16x8*)&Bs[(wc * WNC + fn * 16 + l15) * 64 + ((g ^ (l15 & 7)) * 8)];
            #pragma unroll
            for (int fm = 0; fm < FM; ++fm)
                #pragma unroll
                for (int fn = 0; fn < FN; ++fn)
                    acc[fm][fn] = __builtin_amdgcn_mfma_f32_16x16x32_bf16(
                        af[fm], bfr[fn], acc[fm][fn], 0, 0, 0);
        }
    }

    const int act = mode & 7;
    #pragma unroll
    for (int fm = 0; fm < FM; ++fm) {
        #pragma unroll
        for (int r = 0; r < 4; ++r) {
            const int m = m0 + wr * 64 + fm * 16 + l4 * 4 + r;
            #pragma unroll
            for (int fn = 0; fn < FN; ++fn) {
                const int n = n0 + wc * WNC + fn * 16 + l15;
                float v = acc[fm][fn][r];
                if (bias) v += bias[n];
                if (act == ACT_SILU)      v = silu_f(v);
                else if (act == ACT_GELU) v = gelu_f(v);
                if (mode & OUT_DUAL) {
                    if (n < 768) ((float*)gmul)[(size_t)m * 768 + n] = v;
                    else ((unsigned short*)outp)[(size_t)m * 768 + (n - 768)] = f2bf(v);
                } else {
                    if (gmul)  v *= gmul[(size_t)m * N + n];
                    if (resid) v += resid[(size_t)m * N + n];
                    if (mode & OUT_BF16) ((unsigned short*)outp)[(size_t)m * N + n] = f2bf(v);
                    else                 ((float*)outp)[(size_t)m * N + n] = v;
                }
            }
        }
    }
}

// ---------------------------------------------------------------------------
// MFMA block-causal flash attention, SPLIT over key-blocks (unchanged R8).
// ---------------------------------------------------------------------------
#define PPITCH 72

__global__ __launch_bounds__(256) void attn_mfma(const unsigned short* qkv, const unsigned short* vt,
                                                 float* Opart, float* mpart, float* lpart) {
    __shared__ unsigned short Qs[128 * 64];
    __shared__ unsigned short Ks[2][64 * 64];
    __shared__ unsigned short Vs[2][64 * 64];
    __shared__ unsigned short Pl[128 * PPITCH];

    const int tid  = threadIdx.x;
    const int lane = tid & 63;
    const int w    = tid >> 6;
    const int l15  = lane & 15;
    const int l4   = lane >> 4;
    const int qt   = blockIdx.x;
    const int h    = blockIdx.y;
    const int b    = blockIdx.z / 3;
    const int kb   = blockIdx.z % 3;
    const int i0   = qt * 128;
    const int qb   = qt & 3;

    const size_t bT = (size_t)b * T_SEQ;
    const unsigned short* qp = qkv + bT * QKVC + h * HD;
    const unsigned short* kp = qkv + bT * QKVC + C_DIM + h * HD;
    const size_t vtb = (size_t)(b * NH + h) * HD * T_SEQ;
    const int flat = (b * NH + h) * NQT + qt;

    const int lr   = lane >> 3;
    const int csrc = ((lane & 7) ^ lr) * 8;

    #pragma unroll
    for (int i = 0; i < 4; ++i) {
        const int row = w * 32 + i * 8 + lr;
        gload_lds16(qp + (size_t)(i0 + row) * QKVC + csrc,
                    (char*)Qs + (w * 32 + i * 8) * 128);
    }

    auto stage_kv = [&](int buf, int jt) {
        const int j0 = kb * TBLK + jt * 64;
        #pragma unroll
        for (int i = 0; i < 2; ++i) {
            const int row = w * 8 + i * 32 + lr;
            gload_lds16(kp + (size_t)(j0 + row) * QKVC + csrc,
                        (char*)&Ks[buf][0] + (w * 8 + i * 32) * 128);
            gload_lds16(vt + vtb + (size_t)row * T_SEQ + j0 + csrc,
                        (char*)&Vs[buf][0] + (w * 8 + i * 32) * 128);
        }
    };

    f32x4 o[2][4] = {};
    float m_run[2][4], l_run[2][4];
    #pragma unroll
    for (int a = 0; a < 2; ++a)
        #pragma unroll
        for (int r = 0; r < 4; ++r) { m_run[a][r] = -INFINITY; l_run[a][r] = 0.f; }

    const int jt_max = 2 * qb + 1;
    stage_kv(0, 0);
    int cur = 0;
    for (int jt = 0; jt <= jt_max; ++jt) {
        const bool diag = (jt >= 2 * qb);

        if (jt < jt_max) {
            stage_kv(cur ^ 1, jt + 1);
            WAITCNT_VM(4);
        } else {
            WAITCNT_VM(0);
        }
        __builtin_amdgcn_s_barrier();
        __builtin_amdgcn_sched_barrier(0);

        // ---- S = Q K^T ----
        f32x4 s[2][4] = {};
        #pragma unroll
        for (int kk = 0; kk < 2; ++kk) {
            bf16x8 af[2], bfr[4];
            #pragma unroll
            for (int a = 0; a < 2; ++a)
                af[a] = *(const bf16x8*)&Qs[(w * 32 + a * 16 + l15) * 64 + (((l4 + 4 * kk) ^ (l15 & 7)) * 8)];
            #pragma unroll
            for (int n = 0; n < 4; ++n)
                bfr[n] = *(const bf16x8*)&Ks[cur][(n * 16 + l15) * 64 + (((l4 + 4 * kk) ^ (l15 & 7)) * 8)];
            #pragma unroll
            for (int a = 0; a < 2; ++a)
                #pragma unroll
                for (int n = 0; n < 4; ++n)
                    s[a][n] = __builtin_amdgcn_mfma_f32_16x16x32_bf16(af[a], bfr[n], s[a][n], 0, 0, 0);
        }

        // ---- scale + mask + online softmax + P write ----
        #pragma unroll
        for (int a = 0; a < 2; ++a) {
            #pragma unroll
            for (int r = 0; r < 4; ++r) {
                const int imod = qb * 128 + w * 32 + a * 16 + l4 * 4 + r;
                float pv[4];
                float rowm = -INFINITY;
                #pragma unroll
                for (int n = 0; n < 4; ++n) {
                    float sv = s[a][n][r] * 0.125f;
                    if (diag) {
                        const int jmod = jt * 64 + n * 16 + l15;
                        if (jmod > imod) sv = -INFINITY;
                    }
                    pv[n] = sv;
                    rowm = fmaxf(rowm, sv);
                }
                #pragma unroll
                for (int off = 1; off < 16; off <<= 1) rowm = fmaxf(rowm, __shfl_xor(rowm, off, 64));
                const float mn = fmaxf(m_run[a][r], rowm);
                const float sc = __expf(m_run[a][r] - mn);
                float rs = 0.f;
                #pragma unroll
                for (int n = 0; n < 4; ++n) {
                    const float e = __expf(pv[n] - mn);
                    pv[n] = e;
                    rs += e;
                }
                #pragma unroll
                for (int off = 1; off < 16; off <<= 1) rs += __shfl_xor(rs, off, 64);
                l_run[a][r] = l_run[a][r] * sc + rs;
                m_run[a][r] = mn;
                const int qrow = w * 32 + a * 16 + l4 * 4 + r;
                #pragma unroll
                for (int n = 0; n < 4; ++n) {
                    o[a][n][r] *= sc;
                    Pl[qrow * PPITCH + n * 16 + l15] = f2bf(pv[n]);
                }
            }
        }
        WAITCNT_LGKM0;
        __builtin_amdgcn_s_barrier();
        __builtin_amdgcn_sched_barrier(0);

        // ---- O += P V ----
        #pragma unroll
        for (int kk = 0; kk < 2; ++kk) {
            bf16x8 af[2], bfr[4];
            #pragma unroll
            for (int a = 0; a < 2; ++a)
                af[a] = *(const bf16x8*)&Pl[(w * 32 + a * 16 + l15) * PPITCH + l4 * 8 + kk * 32];
            #pragma unroll
            for (int n = 0; n < 4; ++n)
                bfr[n] = *(const bf16x8*)&Vs[cur][(n * 16 + l15) * 64 + (((l4 + 4 * kk) ^ (l15 & 7)) * 8)];
            #pragma unroll
            for (int a = 0; a < 2; ++a)
                #pragma unroll
                for (int n = 0; n < 4; ++n)
                    o[a][n] = __builtin_amdgcn_mfma_f32_16x16x32_bf16(af[a], bfr[n], o[a][n], 0, 0, 0);
        }

        WAITCNT_LGKM0;
        __builtin_amdgcn_s_barrier();
        __builtin_amdgcn_sched_barrier(0);
        cur ^= 1;
    }

    float* Ob = Opart + ((size_t)kb * NFLAT + flat) * (128 * 64);
    #pragma unroll
    for (int a = 0; a < 2; ++a) {
        #pragma unroll
        for (int r = 0; r < 4; ++r) {
            const int qq = w * 32 + a * 16 + l4 * 4 + r;
            #pragma unroll
            for (int n = 0; n < 4; ++n)
                Ob[(size_t)qq * 64 + n * 16 + l15] = o[a][n][r];
            if (l15 == 0) {
                mpart[((size_t)kb * NFLAT + flat) * 128 + qq] = m_run[a][r];
                lpart[((size_t)kb * NFLAT + flat) * 128 + qq] = l_run[a][r];
            }
        }
    }
}

// ---------------------------------------------------------------------------
// Merge the 3 kb partials (unchanged R8)
// ---------------------------------------------------------------------------
__global__ __launch_bounds__(256) void attn_merge(const float* Opart, const float* mpart, const float* lpart,
                                                  unsigned short* y) {
    const int flat = blockIdx.x;
    const int qt = flat % NQT;
    const int h  = (flat / NQT) % NH;
    const int b  = flat / (NQT * NH);
    const int t  = threadIdx.x;
    const int r  = t >> 1;
    const int c0 = (t & 1) * 32;

    const size_t rowoff = (size_t)flat * 128 + r;
    float m0 = mpart[0 * (size_t)NFLAT * 128 + rowoff];
    float m1 = mpart[1 * (size_t)NFLAT * 128 + rowoff];
    float m2 = mpart[2 * (size_t)NFLAT * 128 + rowoff];
    const float ms = fmaxf(fmaxf(m0, m1), m2);
    const float w0 = __expf(m0 - ms), w1 = __expf(m1 - ms), w2 = __expf(m2 - ms);
    const float ls = lpart[0 * (size_t)NFLAT * 128 + rowoff] * w0 +
                     lpart[1 * (size_t)NFLAT * 128 + rowoff] * w1 +
                     lpart[2 * (size_t)NFLAT * 128 + rowoff] * w2;
    const float inv = 1.0f / ls;

    const size_t obase = ((size_t)flat * 128 + r) * 64 + c0;
    const float* O0 = Opart + 0 * (size_t)NFLAT * 128 * 64 + obase;
    const float* O1 = Opart + 1 * (size_t)NFLAT * 128 * 64 + obase;
    const float* O2 = Opart + 2 * (size_t)NFLAT * 128 * 64 + obase;

    unsigned short* yp = y + ((size_t)b * T_SEQ + qt * 128 + r) * C_DIM + h * HD + c0;
    #pragma unroll
    for (int j = 0; j < 8; ++j) {
        const float4 a = *reinterpret_cast<const float4*>(O0 + j * 4);
        const float4 bq = *reinterpret_cast<const float4*>(O1 + j * 4);
        const float4 cq = *reinterpret_cast<const float4*>(O2 + j * 4);
        ushort4 ov;
        ov.x = f2bf((a.x * w0 + bq.x * w1 + cq.x * w2) * inv);
        ov.y = f2bf((a.y * w0 + bq.y * w1 + cq.y * w2) * inv);
        ov.z = f2bf((a.z * w0 + bq.z * w1 + cq.z * w2) * inv);
        ov.w = f2bf((a.w * w0 + bq.w * w1 + cq.w * w2) * inv);
        *reinterpret_cast<ushort4*>(yp + j * 4) = ov;
    }
}

// ---------------------------------------------------------------------------
// Launcher (layout unchanged from R8)
// ---------------------------------------------------------------------------
extern "C" void kernel_launch(void* const* d_in, const int* in_sizes, int n_in,
                              void* d_out, int out_size, void* d_ws, size_t ws_size,
                              hipStream_t stream) {
    const float* x     = (const float*)d_in[0];
    const float* g1    = (const float*)d_in[1];
    const float* g2    = (const float*)d_in[2];
    const float* W_in  = (const float*)d_in[3];
    const float* b_in  = (const float*)d_in[4];
    const float* W_act = (const float*)d_in[5];
    const float* b_act = (const float*)d_in[6];
    const float* W_out = (const float*)d_in[7];
    const float* b_out = (const float*)d_in[8];
    const float* Wq    = (const float*)d_in[9];
    const float* bq    = (const float*)d_in[10];
    const float* Wk    = (const float*)d_in[11];
    const float* bk    = (const float*)d_in[12];
    const float* Wv    = (const float*)d_in[13];
    const float* bv    = (const float*)d_in[14];
    const float* Wp    = (const float*)d_in[15];
    const float* bp    = (const float*)d_in[16];
    const float* W1    = (const float*)d_in[17];
    const float* b1    = (const float*)d_in[18];
    const float* W2    = (const float*)d_in[19];
    const float* b2    = (const float*)d_in[20];
    float* out = (float*)d_out;

    const float* FNULL = 0;

    float* ws = (float*)d_ws;
    unsigned short* wsb = (unsigned short*)d_ws;
    const size_t U = (size_t)M_ROWS * C_DIM;

    unsigned short* wt = wsb;
    float* qkvb    = ws + 4500000;
    float* actb    = ws + 4505000;
    float* act_res = ws + 1 * U;
    unsigned short* h_bf   = wsb + 4 * U;
    unsigned short* u_bf   = wsb + 5 * U;
    unsigned short* qkv_bf = wsb + 6 * U;
    unsigned short* vt_bf  = wsb + 9 * U;
    unsigned short* y_bf   = wsb + 4 * U;
    unsigned short* g_bf   = wsb + 5 * U;
    float*          x1     = ws  + 3 * U;
    unsigned short* m_bf   = wsb + 8 * U;
    unsigned short* a1_bf  = wsb + 9 * U;
    float* Opart = ws + 5 * U;
    float* mpart = ws + 8 * U;
    float* lpart = ws + 8 * U + (size_t)3 * NFLAT * 128;

    const size_t WCC = (size_t)C_DIM * C_DIM;
    unsigned short* Wt_actin = wt;
    unsigned short* Wt_qkv   = wt + 2 * WCC;
    unsigned short* Wtp      = wt + 5 * WCC;
    unsigned short* Wt_out   = wt + 6 * WCC;
    unsigned short* Wt1      = wt + 7 * WCC;
    unsigned short* Wt2      = Wt1 + (size_t)C_DIM * 4 * C_DIM;

    const dim3 tb(32, 8);
    WPtrs wp;
    wp.p[0] = W_act; wp.p[1] = W_in; wp.p[2] = Wq; wp.p[3] = Wk;
    wp.p[4] = Wv;    wp.p[5] = Wp;   wp.p[6] = W_out;
    wtrans7_kernel<<<dim3(24, 24, 7), tb, 0, stream>>>(wp, wt);
    wtrans_kernel<<<dim3(4 * C_DIM / 32, C_DIM / 32), tb, 0, stream>>>(W1, Wt1, C_DIM, 4 * C_DIM);
    wtrans_kernel<<<dim3(C_DIM / 32, 4 * C_DIM / 32), tb, 0, stream>>>(W2, Wt2, 4 * C_DIM, C_DIM);
    biascat_kernel<<<9, 256, 0, stream>>>(bq, bk, bv, b_act, b_in, qkvb, actb);

    const dim3 blk(256);
    const dim3 g_actin(M_ROWS / 128, 1536 / 128);
    const dim3 g_qkv(M_ROWS / 128, QKVC / 128);
    const dim3 g_cc64(M_ROWS / 64, C_DIM / 128);
    const dim3 g_c4(M_ROWS / 128, 4 * C_DIM / 128);
    const dim3 g_vt(T_SEQ / 32, HD / 32, B_SZ * NH);
    const dim3 g_attn(NQT, NH, B_SZ * 3);

    // h = rmsnorm(x, g1)
    rmsnorm_kernel<<<M_ROWS, blk, 0, stream>>>(x, g1, h_bf);
    // [act_res | u] = silu(h @ [W_act|W_in] + [b_act|b_in])
    gemm_t<128><<<g_actin, blk, 0, stream>>>(h_bf, Wt_actin, actb, act_res, FNULL,
                                             (void*)u_bf, M_ROWS, 1536, C_DIM,
                                             ACT_SILU | OUT_BF16 | OUT_DUAL);
    // qkv = u @ [Wq|Wk|Wv] + b
    gemm_t<128><<<g_qkv, blk, 0, stream>>>(u_bf, Wt_qkv, qkvb, FNULL, FNULL,
                                           (void*)qkv_bf, M_ROWS, QKVC, C_DIM, ACT_NONE | OUT_BF16);
    // vt = head-transpose(v)
    vtrans_kernel<<<g_vt, tb, 0, stream>>>(qkv_bf, vt_bf);
    // attention partials + merge
    attn_mfma<<<g_attn, blk, 0, stream>>>(qkv_bf, vt_bf, Opart, mpart, lpart);
    attn_merge<<<NFLAT, blk, 0, stream>>>(Opart, mpart, lpart, y_bf);
    // g = (y @ Wp + bp) * act_res
    gemm_t<64><<<g_cc64, blk, 0, stream>>>(y_bf, Wtp, bp, act_res, FNULL,
                                           (void*)g_bf, M_ROWS, C_DIM, C_DIM, ACT_NONE | OUT_BF16);
    // x1 = x + g @ W_out + b_out
    gemm_t<64><<<g_cc64, blk, 0, stream>>>(g_bf, Wt_out, b_out, FNULL, x,
                                           (void*)x1, M_ROWS, C_DIM, C_DIM, ACT_NONE);
    // m = rmsnorm(x1, g2)
    rmsnorm_kernel<<<M_ROWS, blk, 0, stream>>>(x1, g2, m_bf);
    // a1 = gelu(m @ W1 + b1)
    gemm_t<128><<<g_c4, blk, 0, stream>>>(m_bf, Wt1, b1, FNULL, FNULL,
                                          (void*)a1_bf, M_ROWS, 4 * C_DIM, C_DIM, ACT_GELU | OUT_BF16);
    // out = x1 + a1 @ W2 + b2
    gemm_t<64><<<g_cc64, blk, 0, stream>>>(a1_bf, Wt2, b2, FNULL, x1,
                                           (void*)out, M_ROWS, C_DIM, 4 * C_DIM, ACT_NONE);
}